// Round 16
// baseline (2186.996 us; speedup 1.0000x reference)
//
#include <hip/hip_runtime.h>
#include <hip/hip_bf16.h>

constexpr int N_   = 131072;
constexpr int G_   = 4096;
constexpr int E_   = 524288;
constexpr int C_   = 96;
constexpr int L_   = 8;
constexpr int FIN_ = 64;
constexpr int TOT_ = N_ + G_;   // 135168 (divisible by 128; N_ divisible by 16)

typedef __attribute__((ext_vector_type(8))) short short8v;
typedef __attribute__((ext_vector_type(4))) float f32x4;
using bf16 = __hip_bfloat16;

__device__ __forceinline__ float silu_f(float y) { return y / (1.f + __expf(-y)); }
__device__ __forceinline__ float toF(float x) { return x; }
__device__ __forceinline__ float toF(bf16 x)  { return __bfloat162float(x); }
__device__ __forceinline__ float bfbits2f(short s) {
  return __uint_as_float(((unsigned)(unsigned short)s) << 16);
}
__device__ __forceinline__ short f2bfbits(float f) {
  bf16 b = __float2bfloat16(f);
  return *reinterpret_cast<short*>(&b);
}
__device__ __forceinline__ void atomAddD(double* p, double v) { unsafeAtomicAdd(p, v); }
__device__ __forceinline__ void atomAddF(float* p, float v)  { unsafeAtomicAdd(p, v); }

static inline int gblk(long n) { return (int)((n + 255) / 256); }

// ======================= preprocessing (all weight transposes fused) =======================
__global__ __launch_bounds__(256) void k_prep(const float* __restrict__ enc_w,
    const float* __restrict__ conv_w1, const float* __restrict__ conv_w2,
    const float* __restrict__ vn_w1, const float* __restrict__ vn_w2,
    bf16* __restrict__ encwT, bf16* __restrict__ w1T, bf16* __restrict__ w2T,
    bf16* __restrict__ vnw1T, bf16* __restrict__ vnw2T) {
  int idx = blockIdx.x * 256 + threadIdx.x;
  const float* src; bf16* dst; int Kd, Nd, local;
  if (idx < 6144)        { src = enc_w;   dst = encwT; Kd = 64;  Nd = 96;  local = idx; }
  else if (idx < 153600) { src = conv_w1; dst = w1T;   Kd = 96;  Nd = 192; local = idx - 6144; }
  else if (idx < 301056) { src = conv_w2; dst = w2T;   Kd = 192; Nd = 96;  local = idx - 153600; }
  else if (idx < 310272) { src = vn_w1;   dst = vnw1T; Kd = 96;  Nd = 96;  local = idx - 301056; }
  else if (idx < 319488) { src = vn_w2;   dst = vnw2T; Kd = 96;  Nd = 96;  local = idx - 310272; }
  else return;
  int per = Kd * Nd;
  int i   = local / per;
  int rem = local - i * per;
  int k   = rem / Nd;
  int n   = rem - k * Nd;
  dst[(size_t)i * per + n * Kd + k] = __float2bfloat16(src[local]);
}

__global__ __launch_bounds__(256) void k_deg_count(const int* __restrict__ tgt, int* __restrict__ deg) {
  int e = blockIdx.x * 256 + threadIdx.x;
  if (e >= E_) return;
  atomicAdd(&deg[tgt[e]], 1);
}

__global__ __launch_bounds__(256) void k_scan_local(const int* __restrict__ deg, int* __restrict__ lp,
                                                    int* __restrict__ bsum) {
  __shared__ int s[256];
  int t = threadIdx.x;
  int i = blockIdx.x * 256 + t;
  int v = deg[i];
  s[t] = v;
  __syncthreads();
  for (int off = 1; off < 256; off <<= 1) {
    int x = (t >= off) ? s[t - off] : 0;
    __syncthreads();
    s[t] += x;
    __syncthreads();
  }
  lp[i] = s[t] - v;
  if (t == 255) bsum[blockIdx.x] = s[255];
}

__global__ __launch_bounds__(512) void k_scan_bsum(const int* __restrict__ bsum, int* __restrict__ boff) {
  __shared__ int s[512];
  int t = threadIdx.x;
  int v = bsum[t];
  s[t] = v;
  __syncthreads();
  for (int off = 1; off < 512; off <<= 1) {
    int x = (t >= off) ? s[t - off] : 0;
    __syncthreads();
    s[t] += x;
    __syncthreads();
  }
  boff[t] = s[t] - v;
}

__global__ __launch_bounds__(256) void k_scan_add(int* __restrict__ rs, const int* __restrict__ boff) {
  int i = blockIdx.x * 256 + threadIdx.x;
  if (i > N_) return;
  if (i == N_) { rs[N_] = E_; return; }
  rs[i] += boff[i >> 8];
}

__global__ __launch_bounds__(256) void k_csr_fill(const int* __restrict__ src, const int* __restrict__ tgt,
                                                  const int* __restrict__ rs, int* __restrict__ cur,
                                                  int* __restrict__ ssrc) {
  int e = blockIdx.x * 256 + threadIdx.x;
  if (e >= E_) return;
  int t = tgt[e];
  int pos = atomicAdd(&cur[t], 1);
  ssrc[rs[t] + pos] = src[e];
}

__global__ __launch_bounds__(256) void k_gbounds(const int* __restrict__ batch, int* __restrict__ gstart) {
  int i = blockIdx.x * 256 + threadIdx.x;
  if (i > N_) return;
  if (i == N_) {
    int last = batch[N_ - 1];
    for (int g = last + 1; g <= G_; ++g) gstart[g] = N_;
    return;
  }
  int b  = batch[i];
  int bp = (i == 0) ? -1 : batch[i - 1];
  for (int g = bp + 1; g <= b; ++g) gstart[g] = i;
}

// ---- degree-balanced permutation (two-level histogram; LPT: heaviest buckets FIRST) ----
__global__ __launch_bounds__(256) void k_deghist(const int* __restrict__ deg, int* __restrict__ hist) {
  __shared__ int lh[33];
  if (threadIdx.x < 33) lh[threadIdx.x] = 0;
  __syncthreads();
  int i = blockIdx.x * 256 + threadIdx.x;
  if (i < N_) {
    int b = deg[i]; if (b > 32) b = 32;
    atomicAdd(&lh[b], 1);
  }
  __syncthreads();
  if (threadIdx.x < 33 && lh[threadIdx.x] != 0) atomicAdd(&hist[threadIdx.x], lh[threadIdx.x]);
}

__global__ __launch_bounds__(64) void k_degbase(const int* __restrict__ hist, int* __restrict__ base) {
  if (threadIdx.x == 0) {
    int acc = 0;
    for (int b = 32; b >= 0; --b) { base[b] = acc; acc += hist[b]; }   // descending: LPT
  }
}

__global__ __launch_bounds__(256) void k_permfill(const int* __restrict__ deg, const int* __restrict__ base,
                                                  int* __restrict__ curs, int* __restrict__ perm) {
  __shared__ int lh[33];
  __shared__ int lbase[33];
  if (threadIdx.x < 33) lh[threadIdx.x] = 0;
  __syncthreads();
  int i = blockIdx.x * 256 + threadIdx.x;
  int b = 0, lpos = 0;
  bool act = (i < N_);
  if (act) {
    b = deg[i]; if (b > 32) b = 32;
    lpos = atomicAdd(&lh[b], 1);
  }
  __syncthreads();
  if (threadIdx.x < 33) {
    int cnt = lh[threadIdx.x];
    lbase[threadIdx.x] = cnt ? atomicAdd(&curs[threadIdx.x], cnt) : 0;
  }
  __syncthreads();
  if (act) perm[base[b] + lbase[b] + lpos] = i;
}

// layer-0 per-graph segment sum of hbf -> vna (fp32)
__global__ __launch_bounds__(192) void k_vnagg(const bf16* __restrict__ hb, const int* __restrict__ gstart,
                                               float* __restrict__ vna) {
  int slot = threadIdx.x / 24;
  int c4   = (threadIdx.x % 24) * 4;
  int g = blockIdx.x * 8 + slot;
  int i0 = gstart[g], i1 = gstart[g + 1];
  float s0 = 0.f, s1 = 0.f, s2 = 0.f, s3 = 0.f;
  for (int i = i0; i < i1; ++i) {
    short4 v = *(const short4*)((const short*)hb + (size_t)i * C_ + c4);
    s0 += bfbits2f(v.x); s1 += bfbits2f(v.y); s2 += bfbits2f(v.z); s3 += bfbits2f(v.w);
  }
  float4 o; o.x = s0; o.y = s1; o.z = s2; o.w = s3;
  *(float4*)(vna + (size_t)g * C_ + c4) = o;
}

// ======================= MFMA GEMM, 512 threads =======================
template <int K, int NOUT, bool INACT, bool OSTATS, bool AF32, typename OutT>
__global__ __launch_bounds__(512) void k_gemm(const void* __restrict__ Aptr, const bf16* __restrict__ Wt,
                                              const float* __restrict__ bias,
                                              const double* __restrict__ stin,
                                              const float* __restrict__ gam, const float* __restrict__ bet,
                                              float Rin,
                                              OutT* __restrict__ out, double* __restrict__ stout) {
  constexpr int KK  = K / 32;
  constexpr int NT  = NOUT / 16;
  constexpr int UPR = K / 8;
  constexpr int LPR = UPR + 1;
  constexpr int LWB  = NOUT * LPR * 16;
  constexpr int ISCB = INACT ? 2 * K * 4 : 0;
  constexpr int SMB  = LWB + (ISCB > 0 ? ISCB : 1);
  __shared__ __align__(16) char smem[SMB];
  uint4* lw   = reinterpret_cast<uint4*>(smem);
  float* lsc  = reinterpret_cast<float*>(smem + LWB);
  float* lsh  = lsc + K;
  float* ssum = reinterpret_cast<float*>(smem);
  float* sqs  = ssum + 8 * NOUT;

  const uint4* wv = (const uint4*)Wt;
  for (int u = threadIdx.x; u < NOUT * UPR; u += 512) {
    int row = u / UPR, colu = u - row * UPR;
    lw[row * LPR + colu] = wv[u];
  }
  if (INACT) {
    for (int k = threadIdx.x; k < K; k += 512) {
      double mean = stin[k] / (double)Rin;
      double var  = stin[K + k] / (double)Rin - mean * mean;
      float sc = gam[k] * rsqrtf((float)var + 1e-5f);
      lsc[k] = sc;
      lsh[k] = bet[k] - (float)mean * sc;
    }
  }

  int wave = threadIdx.x >> 6, lane = threadIdx.x & 63;
  int m0 = (blockIdx.x * 8 + wave) * 16;
  int lr = lane & 15, lg = lane >> 4;

  short8v a[KK];
  if constexpr (AF32) {
    const float* Arow = (const float*)Aptr + (size_t)(m0 + lr) * K + lg * 8;
#pragma unroll
    for (int kk = 0; kk < KK; ++kk) {
      float4 f0 = *(const float4*)(Arow + kk * 32);
      float4 f1 = *(const float4*)(Arow + kk * 32 + 4);
      a[kk][0] = f2bfbits(f0.x); a[kk][1] = f2bfbits(f0.y);
      a[kk][2] = f2bfbits(f0.z); a[kk][3] = f2bfbits(f0.w);
      a[kk][4] = f2bfbits(f1.x); a[kk][5] = f2bfbits(f1.y);
      a[kk][6] = f2bfbits(f1.z); a[kk][7] = f2bfbits(f1.w);
    }
  } else {
    const short* Arow = (const short*)Aptr + (size_t)(m0 + lr) * K + lg * 8;
#pragma unroll
    for (int kk = 0; kk < KK; ++kk) a[kk] = *(const short8v*)(Arow + kk * 32);
  }

  __syncthreads();

  if (INACT) {
#pragma unroll
    for (int kk = 0; kk < KK; ++kk) {
      int kbase = kk * 32 + lg * 8;
#pragma unroll
      for (int j = 0; j < 8; ++j) {
        float f = bfbits2f(a[kk][j]);
        f = silu_f(fmaf(f, lsc[kbase + j], lsh[kbase + j]));
        a[kk][j] = f2bfbits(f);
      }
    }
  }

  f32x4 acc[NT];
#pragma unroll
  for (int nt = 0; nt < NT; ++nt) acc[nt] = (f32x4){0.f, 0.f, 0.f, 0.f};

#pragma unroll
  for (int nt = 0; nt < NT; ++nt) {
    const short* brow = (const short*)&lw[(nt * 16 + lr) * LPR] + lg * 8;
#pragma unroll
    for (int kk = 0; kk < KK; ++kk) {
      short8v b = *(const short8v*)(brow + kk * 32);
      acc[nt] = __builtin_amdgcn_mfma_f32_16x16x32_bf16(a[kk], b, acc[nt], 0, 0, 0);
    }
  }

  if (OSTATS) __syncthreads();

  int orow = m0 + (lg << 2);
#pragma unroll
  for (int nt = 0; nt < NT; ++nt) {
    int col = nt * 16 + lr;
    float bi = bias[col];
    float s = 0.f, q = 0.f;
#pragma unroll
    for (int r = 0; r < 4; ++r) {
      float y = acc[nt][r] + bi;
      float yb;
      size_t off = (size_t)(orow + r) * NOUT + col;
      if constexpr (sizeof(OutT) == 2) {
        short bits = f2bfbits(y);
        ((short*)out)[off] = bits;
        yb = bfbits2f(bits);
      } else {
        ((float*)out)[off] = y;
        yb = y;
      }
      if (OSTATS) { s += yb; q += yb * yb; }
    }
    if (OSTATS) {
      s += __shfl_xor(s, 16, 64); s += __shfl_xor(s, 32, 64);
      q += __shfl_xor(q, 16, 64); q += __shfl_xor(q, 32, 64);
      if (lg == 0) { ssum[wave * NOUT + col] = s; sqs[wave * NOUT + col] = q; }
    }
  }
  if (OSTATS) {
    __syncthreads();
    int tid = threadIdx.x;
    if (tid < NOUT) {
      float s = 0.f, q = 0.f;
#pragma unroll
      for (int w = 0; w < 8; ++w) { s += ssum[w * NOUT + tid]; q += sqs[w * NOUT + tid]; }
      atomAddD(&stout[tid], (double)s);
      atomAddD(&stout[NOUT + tid], (double)q);
    }
  }
}

// ===== fused aggregate + GEMM1 (+stats): wave-level WORK STEALING over 16-row items =========
// Grid sized to residency (768 blocks x 8 waves); each wave pulls items off a global counter.
// Items are LPT-ordered via perm (heavy-degree first); VN items (lightest) come last.
// Stats accumulate in a per-wave private LDS region (separate from the weight tile).
template <int K, int NOUT>   // K=96, NOUT=192
__global__ __launch_bounds__(512) void k_gemm_agg(const bf16* __restrict__ hb,
    const int* __restrict__ batch, const int* __restrict__ rs, const int* __restrict__ ssrc,
    const float* __restrict__ vna, const int* __restrict__ perm,
    const bf16* __restrict__ Wt, const float* __restrict__ bias,
    bf16* __restrict__ out, double* __restrict__ st, int* __restrict__ ctr) {
  constexpr int KK  = K / 32;
  constexpr int NT  = NOUT / 16;
  constexpr int UPR = K / 8;
  constexpr int LPR = UPR + 1;
  constexpr int LWB = NOUT * LPR * 16;   // 39936
  constexpr int STW = 8 * NOUT;          // per-array stat floats
  __shared__ __align__(16) char smem[LWB + 2 * STW * 4];   // 52224 B -> 3 blocks/CU
  uint4* lw    = reinterpret_cast<uint4*>(smem);
  float* lds_s = reinterpret_cast<float*>(smem + LWB);
  float* lds_q = lds_s + STW;

  const uint4* wv = (const uint4*)Wt;
  for (int u = threadIdx.x; u < NOUT * UPR; u += 512) {
    int row = u / UPR, colu = u - row * UPR;
    lw[row * LPR + colu] = wv[u];
  }
  for (int u = threadIdx.x; u < STW; u += 512) { lds_s[u] = 0.f; lds_q[u] = 0.f; }
  __syncthreads();

  int wave = threadIdx.x >> 6, lane = threadIdx.x & 63;
  int lr = lane & 15, lg = lane >> 4;
  int koff = lg * 8;

  auto hrow = [&](int r) { return (const short*)hb + (size_t)r * K; };

  for (;;) {
    int it;
    if (lane == 0) it = atomicAdd(ctr, 1);
    it = __shfl(it, 0, 64);
    if (it >= TOT_ / 16) break;

    int m0 = it * 16;
    int row = m0 + lr;
    int rowo = (m0 < N_) ? perm[row] : row;

    float av[KK * 8];
#pragma unroll
    for (int t = 0; t < KK * 8; ++t) av[t] = 0.f;

    auto addPtr = [&](const short* p) {
#pragma unroll
      for (int kk = 0; kk < KK; ++kk) {
        short8v v = *(const short8v*)(p + koff + kk * 32);
#pragma unroll
        for (int j = 0; j < 8; ++j) av[kk * 8 + j] += bfbits2f(v[j]);
      }
    };
    auto addPtr2 = [&](const short* p0, const short* p1) {
      short8v v0[KK], v1[KK];
#pragma unroll
      for (int kk = 0; kk < KK; ++kk) {
        v0[kk] = *(const short8v*)(p0 + koff + kk * 32);
        v1[kk] = *(const short8v*)(p1 + koff + kk * 32);
      }
#pragma unroll
      for (int kk = 0; kk < KK; ++kk)
#pragma unroll
        for (int j = 0; j < 8; ++j)
          av[kk * 8 + j] += bfbits2f(v0[kk][j]) + bfbits2f(v1[kk][j]);
    };

    if (m0 < N_) {
      addPtr2(hrow(rowo), hrow(N_ + batch[rowo]));
      int e = rs[rowo], e1 = rs[rowo + 1];
      for (; e + 2 <= e1; e += 2) addPtr2(hrow(ssrc[e]), hrow(ssrc[e + 1]));
      if (e < e1) addPtr(hrow(ssrc[e]));
    } else {
      addPtr(hrow(rowo));
      const float* vp = vna + (size_t)(rowo - N_) * K + koff;
#pragma unroll
      for (int kk = 0; kk < KK; ++kk) {
        float4 f0 = *(const float4*)(vp + kk * 32);
        float4 f1 = *(const float4*)(vp + kk * 32 + 4);
        av[kk * 8 + 0] += f0.x; av[kk * 8 + 1] += f0.y; av[kk * 8 + 2] += f0.z; av[kk * 8 + 3] += f0.w;
        av[kk * 8 + 4] += f1.x; av[kk * 8 + 5] += f1.y; av[kk * 8 + 6] += f1.z; av[kk * 8 + 7] += f1.w;
      }
    }

    short8v a[KK];
#pragma unroll
    for (int kk = 0; kk < KK; ++kk)
#pragma unroll
      for (int j = 0; j < 8; ++j) a[kk][j] = f2bfbits(av[kk * 8 + j]);

    f32x4 acc[NT];
#pragma unroll
    for (int nt = 0; nt < NT; ++nt) acc[nt] = (f32x4){0.f, 0.f, 0.f, 0.f};

#pragma unroll
    for (int nt = 0; nt < NT; ++nt) {
      const short* brow = (const short*)&lw[(nt * 16 + lr) * LPR] + lg * 8;
#pragma unroll
      for (int kk = 0; kk < KK; ++kk) {
        short8v b = *(const short8v*)(brow + kk * 32);
        acc[nt] = __builtin_amdgcn_mfma_f32_16x16x32_bf16(a[kk], b, acc[nt], 0, 0, 0);
      }
    }

    int rid[4];
#pragma unroll
    for (int r = 0; r < 4; ++r) rid[r] = __shfl(rowo, (lg << 2) + r, 64);

#pragma unroll
    for (int nt = 0; nt < NT; ++nt) {
      int col = nt * 16 + lr;
      float bi = bias[col];
      float s = 0.f, q = 0.f;
#pragma unroll
      for (int r = 0; r < 4; ++r) {
        float y = acc[nt][r] + bi;
        short bits = f2bfbits(y);
        ((short*)out)[(size_t)rid[r] * NOUT + col] = bits;
        float yb = bfbits2f(bits);
        s += yb; q += yb * yb;
      }
      s += __shfl_xor(s, 16, 64); s += __shfl_xor(s, 32, 64);
      q += __shfl_xor(q, 16, 64); q += __shfl_xor(q, 32, 64);
      if (lg == 0) {
        lds_s[wave * NOUT + col] += s;   // per-wave private region: no race
        lds_q[wave * NOUT + col] += q;
      }
    }
  }

  __syncthreads();
  int tid = threadIdx.x;
  if (tid < NOUT) {
    float s = 0.f, q = 0.f;
#pragma unroll
    for (int w = 0; w < 8; ++w) { s += lds_s[w * NOUT + tid]; q += lds_q[w * NOUT + tid]; }
    atomAddD(&st[tid], (double)s);
    atomAddD(&st[NOUT + tid], (double)q);
  }
}

__global__ __launch_bounds__(256) void k_fill_vn(bf16* __restrict__ hb, const float* __restrict__ vn) {
  int idx = blockIdx.x * 256 + threadIdx.x;
  if (idx >= G_ * C_) return;
  int c = idx % C_;
  hb[(size_t)N_ * C_ + idx] = __float2bfloat16(vn[c]);
}

template <int CC, typename T>
__global__ __launch_bounds__(256) void k_bnstats(const T* __restrict__ X, int R, double* __restrict__ st) {
  int c = threadIdx.x;
  float s = 0.f, q = 0.f;
  for (int r = blockIdx.x; r < R; r += gridDim.x) {
    float v = toF(X[(size_t)r * CC + c]);
    s += v;
    q += v * v;
  }
  atomAddD(&st[c], (double)s);
  atomAddD(&st[CC + c], (double)q);
}

template <int CC>
__global__ __launch_bounds__(256) void k_bnfin(const double* __restrict__ st, int R,
    const float* __restrict__ g, const float* __restrict__ be,
    float* __restrict__ scale, float* __restrict__ shift) {
  int c = threadIdx.x;
  if (c >= CC) return;
  double mean = st[c] / R;
  double var  = st[CC + c] / R - mean * mean;
  float sc = g[c] * rsqrtf((float)var + 1e-5f);
  scale[c] = sc;
  shift[c] = be[c] - (float)mean * sc;
}

// hb = (resid ? hb : 0) + silu(bn(Z)); 192 threads = 16 rows; fused per-graph vna accumulation
__global__ __launch_bounds__(192) void k_update(const bf16* __restrict__ Z, bf16* __restrict__ hb,
    const double* __restrict__ st,
    const float* __restrict__ gam, const float* __restrict__ bet, int addResid,
    float* __restrict__ vna, const int* __restrict__ batch, int accvna) {
  __shared__ float lsc[C_], lsh[C_];
  __shared__ float lh[16][C_];
  __shared__ int   lbatch[16];
  int t = threadIdx.x;
  if (t < C_) {
    double mean = st[t] / (double)TOT_;
    double var  = st[C_ + t] / (double)TOT_ - mean * mean;
    float sc = gam[t] * rsqrtf((float)var + 1e-5f);
    lsc[t] = sc;
    lsh[t] = bet[t] - (float)mean * sc;
  }
  int r0 = blockIdx.x * 16;
  int nodeBlk = (r0 < N_);            // N_ % 16 == 0: blocks never straddle
  if (accvna && nodeBlk && t < 16) lbatch[t] = batch[r0 + t];
  __syncthreads();

  int rl = t / 12;                    // 0..15
  int cg = t - rl * 12;               // 0..11
  int c0 = cg * 8;
  size_t vidx = (size_t)(r0 + rl) * 12 + cg;
  short8v zv = ((const short8v*)Z)[vidx];
  short8v hv = ((const short8v*)hb)[vidx];
  short8v o;
  float hn[8];
#pragma unroll
  for (int j = 0; j < 8; ++j) {
    float y = silu_f(fmaf(bfbits2f(zv[j]), lsc[c0 + j], lsh[c0 + j]));
    hn[j] = addResid ? (bfbits2f(hv[j]) + y) : y;
    o[j] = f2bfbits(hn[j]);
  }
  ((short8v*)hb)[vidx] = o;

  if (accvna && nodeBlk) {
#pragma unroll
    for (int j = 0; j < 8; ++j) lh[rl][c0 + j] = hn[j];
    __syncthreads();
    if (t < C_) {
      int c = t;
      float run = 0.f;
      int g = lbatch[0];
      for (int r = 0; r < 16; ++r) {
        int gb = lbatch[r];
        if (gb != g) { atomAddF(&vna[(size_t)g * C_ + c], run); run = 0.f; g = gb; }
        run += lh[r][c];
      }
      atomAddF(&vna[(size_t)g * C_ + c], run);
    }
  }
}

template <int K, int M, bool INACT>
__global__ __launch_bounds__(256) void k_mm(const float* __restrict__ A,
    const float* __restrict__ W, const float* __restrict__ bias,
    const float* __restrict__ isc, const float* __restrict__ ish,
    float* __restrict__ out, int R) {
  int idx = blockIdx.x * 256 + threadIdx.x;
  if (idx >= R * M) return;
  int row = idx / M;
  int m   = idx - row * M;
  const float* ar = A + (size_t)row * K;
  float s = bias[m];
#pragma unroll 8
  for (int k = 0; k < K; ++k) {
    float a = ar[k];
    if (INACT) a = silu_f(fmaf(a, isc[k], ish[k]));
    s = fmaf(a, W[k * M + m], s);
  }
  out[idx] = s;
}

__global__ __launch_bounds__(256) void k_pool2(const bf16* __restrict__ hb, const int* __restrict__ gstart,
                                               float* __restrict__ pooled) {
  int idx = blockIdx.x * 256 + threadIdx.x;
  if (idx >= G_ * C_) return;
  int g = idx / C_;
  int c = idx - g * C_;
  int i0 = gstart[g], i1 = gstart[g + 1];
  float s = 0.f;
  for (int i = i0; i < i1; ++i) s += toF(hb[(size_t)i * C_ + c]);
  pooled[idx] = s / fmaxf((float)(i1 - i0), 1.0f);
}

extern "C" void kernel_launch(void* const* d_in, const int* in_sizes, int n_in,
                              void* d_out, int out_size, void* d_ws, size_t ws_size,
                              hipStream_t stream) {
  (void)in_sizes; (void)n_in; (void)out_size; (void)ws_size;
  const float* x       = (const float*)d_in[0];
  const int*   ei      = (const int*)d_in[1];
  const int*   batch   = (const int*)d_in[2];
  const float* enc_w   = (const float*)d_in[4];
  const float* enc_b   = (const float*)d_in[5];
  const float* vn_emb  = (const float*)d_in[6];
  const float* vn_w1   = (const float*)d_in[7];
  const float* vn_b1   = (const float*)d_in[8];
  const float* vn_g1   = (const float*)d_in[9];
  const float* vn_be1  = (const float*)d_in[10];
  const float* vn_w2   = (const float*)d_in[11];
  const float* vn_b2   = (const float*)d_in[12];
  const float* conv_w1 = (const float*)d_in[13];
  const float* conv_b1 = (const float*)d_in[14];
  const float* conv_g1 = (const float*)d_in[15];
  const float* conv_be1= (const float*)d_in[16];
  const float* conv_w2 = (const float*)d_in[17];
  const float* conv_b2 = (const float*)d_in[18];
  const float* bn_g    = (const float*)d_in[19];
  const float* bn_b    = (const float*)d_in[20];
  const float* h_w1    = (const float*)d_in[21];
  const float* h_b1    = (const float*)d_in[22];
  const float* h_g1    = (const float*)d_in[23];
  const float* h_be1   = (const float*)d_in[24];
  const float* h_w2    = (const float*)d_in[25];
  const float* h_b2    = (const float*)d_in[26];
  const float* h_g2    = (const float*)d_in[27];
  const float* h_be2   = (const float*)d_in[28];
  const float* h_w3    = (const float*)d_in[29];
  const float* h_b3    = (const float*)d_in[30];
  float* out = (float*)d_out;

  const int* e_src = ei;
  const int* e_tgt = ei + E_;

  char* p = (char*)d_ws;
  auto alloc = [&](size_t bytes) -> char* {
    char* r = p;
    p += (bytes + 15) & ~size_t(15);
    return r;
  };
  bf16*   hbf    = (bf16*)  alloc((size_t)TOT_ * C_ * 2);
  float*  vnaf   = (float*) alloc((size_t)G_ * C_ * 4);
  bf16*   vtb    = (bf16*)  alloc((size_t)G_ * C_ * 2);
  float*  pooled = (float*) alloc((size_t)G_ * C_ * 4);
  float*  t1     = (float*) alloc((size_t)G_ * 48 * 4);
  float*  t2     = (float*) alloc((size_t)G_ * 24 * 4);
  float*  scale1 = (float*) alloc(256 * 4);
  float*  shift1 = (float*) alloc(256 * 4);
  float*  scale2 = (float*) alloc(256 * 4);
  float*  shift2 = (float*) alloc(256 * 4);
  double* stbuf  = (double*)alloc((size_t)26 * 384 * 8);
  bf16*   z1     = (bf16*)  alloc((size_t)TOT_ * 2 * C_ * 2);
  bf16*   z2     = (bf16*)  alloc((size_t)TOT_ * C_ * 2);
  bf16*   encwT  = (bf16*)  alloc((size_t)C_ * FIN_ * 2);
  bf16*   w1T    = (bf16*)  alloc((size_t)L_ * 2 * C_ * C_ * 2);
  bf16*   w2T    = (bf16*)  alloc((size_t)L_ * C_ * 2 * C_ * 2);
  bf16*   vnw1T  = (bf16*)  alloc((size_t)C_ * C_ * 2);
  bf16*   vnw2T  = (bf16*)  alloc((size_t)C_ * C_ * 2);
  int*    deg    = (int*)   alloc((size_t)N_ * 4);
  int*    cur    = (int*)   alloc((size_t)N_ * 4);
  int*    rs     = (int*)   alloc((size_t)(N_ + 1) * 4);
  int*    bsum   = (int*)   alloc(512 * 4);
  int*    boff   = (int*)   alloc(512 * 4);
  int*    ssrc   = (int*)   alloc((size_t)E_ * 4);
  int*    gstart = (int*)   alloc((size_t)(G_ + 1) * 4);
  int*    perm   = (int*)   alloc((size_t)N_ * 4);
  int*    hist   = (int*)   alloc(33 * 4);
  int*    hbase  = (int*)   alloc(33 * 4);
  int*    hcurs  = (int*)   alloc(33 * 4);
  int*    aggctr = (int*)   alloc(32 * 4);   // per-layer steal counters

  auto ST = [&](int i) { return stbuf + (size_t)i * 384; };

  // ---- preprocessing ----
  k_prep<<<gblk(319488), 256, 0, stream>>>(enc_w, conv_w1, conv_w2, vn_w1, vn_w2,
                                           encwT, w1T, w2T, vnw1T, vnw2T);

  hipMemsetAsync(deg, 0, (size_t)N_ * 4, stream);
  hipMemsetAsync(cur, 0, (size_t)N_ * 4, stream);
  hipMemsetAsync(stbuf, 0, (size_t)26 * 384 * 8, stream);
  hipMemsetAsync(hist, 0, 33 * 4, stream);
  hipMemsetAsync(hcurs, 0, 33 * 4, stream);
  hipMemsetAsync(aggctr, 0, 32 * 4, stream);
  k_deg_count<<<gblk(E_), 256, 0, stream>>>(e_tgt, deg);
  k_scan_local<<<N_ / 256, 256, 0, stream>>>(deg, rs, bsum);
  k_scan_bsum<<<1, 512, 0, stream>>>(bsum, boff);
  k_scan_add<<<gblk(N_ + 1), 256, 0, stream>>>(rs, boff);
  k_csr_fill<<<gblk(E_), 256, 0, stream>>>(e_src, e_tgt, rs, cur, ssrc);
  k_gbounds<<<gblk(N_ + 1), 256, 0, stream>>>(batch, gstart);
  k_deghist<<<gblk(N_), 256, 0, stream>>>(deg, hist);
  k_degbase<<<1, 64, 0, stream>>>(hist, hbase);
  k_permfill<<<gblk(N_), 256, 0, stream>>>(deg, hbase, hcurs, perm);

  // ---- encoder + VN init ----
  k_gemm<FIN_, C_, false, false, true, bf16><<<N_ / 128, 512, 0, stream>>>(
      x, encwT, enc_b, nullptr, nullptr, nullptr, 1.f, hbf, nullptr);
  k_fill_vn<<<gblk((long)G_ * C_), 256, 0, stream>>>(hbf, vn_emb);
  k_vnagg<<<G_ / 8, 192, 0, stream>>>(hbf, gstart, vnaf);

  // ---- 8 conv layers ----
  for (int i = 0; i < L_; ++i) {
    const bf16*  wt1 = w1T + (size_t)i * 2 * C_ * C_;
    const bf16*  wt2 = w2T + (size_t)i * C_ * 2 * C_;
    const float* b1  = conv_b1 + (size_t)i * 2 * C_;
    const float* g1  = conv_g1 + (size_t)i * 2 * C_;
    const float* be1 = conv_be1+ (size_t)i * 2 * C_;
    const float* b2  = conv_b2 + (size_t)i * C_;
    const float* bg  = bn_g    + (size_t)i * C_;
    const float* bb  = bn_b    + (size_t)i * C_;
    int accvna = (i < L_ - 1);

    k_gemm_agg<C_, 2 * C_><<<768, 512, 0, stream>>>(
        hbf, batch, rs, ssrc, vnaf, perm, wt1, b1, z1, ST(i), aggctr + i);

    k_gemm<2 * C_, C_, true, true, false, bf16><<<TOT_ / 128, 512, 0, stream>>>(
        z1, wt2, b2, ST(i), g1, be1, (float)TOT_, z2, ST(8 + i));

    if (accvna) hipMemsetAsync(vnaf, 0, (size_t)G_ * C_ * 4, stream);
    k_update<<<TOT_ / 16, 192, 0, stream>>>(z2, hbf, ST(8 + i), bg, bb, i > 0,
                                            vnaf, batch, accvna);

    if (i < L_ - 1) {
      k_gemm<C_, C_, false, true, false, bf16><<<G_ / 128, 512, 0, stream>>>(
          hbf + (size_t)N_ * C_, vnw1T, vn_b1, nullptr, nullptr, nullptr, 1.f, vtb, ST(16 + i));
      k_gemm<C_, C_, true, false, false, bf16><<<G_ / 128, 512, 0, stream>>>(
          vtb, vnw2T, vn_b2, ST(16 + i), vn_g1, vn_be1, (float)G_,
          hbf + (size_t)N_ * C_, nullptr);
    }
  }

  // ---- mean pool ----
  k_pool2<<<gblk((long)G_ * C_), 256, 0, stream>>>(hbf, gstart, pooled);

  // ---- head MLP ----
  k_mm<C_, 48, false><<<gblk((long)G_ * 48), 256, 0, stream>>>(
      pooled, h_w1, h_b1, nullptr, nullptr, t1, G_);
  k_bnstats<48, float><<<64, 48, 0, stream>>>(t1, G_, ST(23));
  k_bnfin<48><<<1, 48, 0, stream>>>(ST(23), G_, h_g1, h_be1, scale1, shift1);

  k_mm<48, 24, true><<<gblk((long)G_ * 24), 256, 0, stream>>>(
      t1, h_w2, h_b2, scale1, shift1, t2, G_);
  k_bnstats<24, float><<<64, 24, 0, stream>>>(t2, G_, ST(24));
  k_bnfin<24><<<1, 24, 0, stream>>>(ST(24), G_, h_g2, h_be2, scale2, shift2);

  k_mm<24, 5, true><<<gblk((long)G_ * 5), 256, 0, stream>>>(
      t2, h_w3, h_b3, scale2, shift2, out, G_);
}

// Round 17
// 2186.474 us; speedup vs baseline: 1.0002x; 1.0002x over previous
//
#include <hip/hip_runtime.h>
#include <hip/hip_bf16.h>

constexpr int N_   = 131072;
constexpr int G_   = 4096;
constexpr int E_   = 524288;
constexpr int C_   = 96;
constexpr int L_   = 8;
constexpr int FIN_ = 64;
constexpr int TOT_ = N_ + G_;   // 135168 (divisible by 128; N_ divisible by 16)

typedef __attribute__((ext_vector_type(8))) short short8v;
typedef __attribute__((ext_vector_type(4))) float f32x4;
using bf16 = __hip_bfloat16;

__device__ __forceinline__ float silu_f(float y) { return y / (1.f + __expf(-y)); }
__device__ __forceinline__ float toF(float x) { return x; }
__device__ __forceinline__ float toF(bf16 x)  { return __bfloat162float(x); }
__device__ __forceinline__ float bfbits2f(short s) {
  return __uint_as_float(((unsigned)(unsigned short)s) << 16);
}
__device__ __forceinline__ short f2bfbits(float f) {
  bf16 b = __float2bfloat16(f);
  return *reinterpret_cast<short*>(&b);
}
__device__ __forceinline__ void atomAddD(double* p, double v) { unsafeAtomicAdd(p, v); }
__device__ __forceinline__ void atomAddF(float* p, float v)  { unsafeAtomicAdd(p, v); }

static inline int gblk(long n) { return (int)((n + 255) / 256); }

// ======================= preprocessing (all weight transposes fused) =======================
__global__ __launch_bounds__(256) void k_prep(const float* __restrict__ enc_w,
    const float* __restrict__ conv_w1, const float* __restrict__ conv_w2,
    const float* __restrict__ vn_w1, const float* __restrict__ vn_w2,
    bf16* __restrict__ encwT, bf16* __restrict__ w1T, bf16* __restrict__ w2T,
    bf16* __restrict__ vnw1T, bf16* __restrict__ vnw2T) {
  int idx = blockIdx.x * 256 + threadIdx.x;
  const float* src; bf16* dst; int Kd, Nd, local;
  if (idx < 6144)        { src = enc_w;   dst = encwT; Kd = 64;  Nd = 96;  local = idx; }
  else if (idx < 153600) { src = conv_w1; dst = w1T;   Kd = 96;  Nd = 192; local = idx - 6144; }
  else if (idx < 301056) { src = conv_w2; dst = w2T;   Kd = 192; Nd = 96;  local = idx - 153600; }
  else if (idx < 310272) { src = vn_w1;   dst = vnw1T; Kd = 96;  Nd = 96;  local = idx - 301056; }
  else if (idx < 319488) { src = vn_w2;   dst = vnw2T; Kd = 96;  Nd = 96;  local = idx - 310272; }
  else return;
  int per = Kd * Nd;
  int i   = local / per;
  int rem = local - i * per;
  int k   = rem / Nd;
  int n   = rem - k * Nd;
  dst[(size_t)i * per + n * Kd + k] = __float2bfloat16(src[local]);
}

__global__ __launch_bounds__(256) void k_deg_count(const int* __restrict__ tgt, int* __restrict__ deg) {
  int e = blockIdx.x * 256 + threadIdx.x;
  if (e >= E_) return;
  atomicAdd(&deg[tgt[e]], 1);
}

__global__ __launch_bounds__(256) void k_scan_local(const int* __restrict__ deg, int* __restrict__ lp,
                                                    int* __restrict__ bsum) {
  __shared__ int s[256];
  int t = threadIdx.x;
  int i = blockIdx.x * 256 + t;
  int v = deg[i];
  s[t] = v;
  __syncthreads();
  for (int off = 1; off < 256; off <<= 1) {
    int x = (t >= off) ? s[t - off] : 0;
    __syncthreads();
    s[t] += x;
    __syncthreads();
  }
  lp[i] = s[t] - v;
  if (t == 255) bsum[blockIdx.x] = s[255];
}

__global__ __launch_bounds__(512) void k_scan_bsum(const int* __restrict__ bsum, int* __restrict__ boff) {
  __shared__ int s[512];
  int t = threadIdx.x;
  int v = bsum[t];
  s[t] = v;
  __syncthreads();
  for (int off = 1; off < 512; off <<= 1) {
    int x = (t >= off) ? s[t - off] : 0;
    __syncthreads();
    s[t] += x;
    __syncthreads();
  }
  boff[t] = s[t] - v;
}

__global__ __launch_bounds__(256) void k_scan_add(int* __restrict__ rs, const int* __restrict__ boff) {
  int i = blockIdx.x * 256 + threadIdx.x;
  if (i > N_) return;
  if (i == N_) { rs[N_] = E_; return; }
  rs[i] += boff[i >> 8];
}

__global__ __launch_bounds__(256) void k_csr_fill(const int* __restrict__ src, const int* __restrict__ tgt,
                                                  const int* __restrict__ rs, int* __restrict__ cur,
                                                  int* __restrict__ ssrc) {
  int e = blockIdx.x * 256 + threadIdx.x;
  if (e >= E_) return;
  int t = tgt[e];
  int pos = atomicAdd(&cur[t], 1);
  ssrc[rs[t] + pos] = src[e];
}

__global__ __launch_bounds__(256) void k_gbounds(const int* __restrict__ batch, int* __restrict__ gstart) {
  int i = blockIdx.x * 256 + threadIdx.x;
  if (i > N_) return;
  if (i == N_) {
    int last = batch[N_ - 1];
    for (int g = last + 1; g <= G_; ++g) gstart[g] = N_;
    return;
  }
  int b  = batch[i];
  int bp = (i == 0) ? -1 : batch[i - 1];
  for (int g = bp + 1; g <= b; ++g) gstart[g] = i;
}

// ---- degree-balanced permutation (two-level histogram; LPT: heaviest buckets FIRST) ----
__global__ __launch_bounds__(256) void k_deghist(const int* __restrict__ deg, int* __restrict__ hist) {
  __shared__ int lh[33];
  if (threadIdx.x < 33) lh[threadIdx.x] = 0;
  __syncthreads();
  int i = blockIdx.x * 256 + threadIdx.x;
  if (i < N_) {
    int b = deg[i]; if (b > 32) b = 32;
    atomicAdd(&lh[b], 1);
  }
  __syncthreads();
  if (threadIdx.x < 33 && lh[threadIdx.x] != 0) atomicAdd(&hist[threadIdx.x], lh[threadIdx.x]);
}

__global__ __launch_bounds__(64) void k_degbase(const int* __restrict__ hist, int* __restrict__ base) {
  if (threadIdx.x == 0) {
    int acc = 0;
    for (int b = 32; b >= 0; --b) { base[b] = acc; acc += hist[b]; }   // descending: LPT
  }
}

__global__ __launch_bounds__(256) void k_permfill(const int* __restrict__ deg, const int* __restrict__ base,
                                                  int* __restrict__ curs, int* __restrict__ perm) {
  __shared__ int lh[33];
  __shared__ int lbase[33];
  if (threadIdx.x < 33) lh[threadIdx.x] = 0;
  __syncthreads();
  int i = blockIdx.x * 256 + threadIdx.x;
  int b = 0, lpos = 0;
  bool act = (i < N_);
  if (act) {
    b = deg[i]; if (b > 32) b = 32;
    lpos = atomicAdd(&lh[b], 1);
  }
  __syncthreads();
  if (threadIdx.x < 33) {
    int cnt = lh[threadIdx.x];
    lbase[threadIdx.x] = cnt ? atomicAdd(&curs[threadIdx.x], cnt) : 0;
  }
  __syncthreads();
  if (act) perm[base[b] + lbase[b] + lpos] = i;
}

// layer-0 per-graph segment sum of hbf -> vna (fp32)
__global__ __launch_bounds__(192) void k_vnagg(const bf16* __restrict__ hb, const int* __restrict__ gstart,
                                               float* __restrict__ vna) {
  int slot = threadIdx.x / 24;
  int c4   = (threadIdx.x % 24) * 4;
  int g = blockIdx.x * 8 + slot;
  int i0 = gstart[g], i1 = gstart[g + 1];
  float s0 = 0.f, s1 = 0.f, s2 = 0.f, s3 = 0.f;
  for (int i = i0; i < i1; ++i) {
    short4 v = *(const short4*)((const short*)hb + (size_t)i * C_ + c4);
    s0 += bfbits2f(v.x); s1 += bfbits2f(v.y); s2 += bfbits2f(v.z); s3 += bfbits2f(v.w);
  }
  float4 o; o.x = s0; o.y = s1; o.z = s2; o.w = s3;
  *(float4*)(vna + (size_t)g * C_ + c4) = o;
}

// ======================= MFMA GEMM, 512 threads =======================
template <int K, int NOUT, bool INACT, bool OSTATS, bool AF32, typename OutT>
__global__ __launch_bounds__(512) void k_gemm(const void* __restrict__ Aptr, const bf16* __restrict__ Wt,
                                              const float* __restrict__ bias,
                                              const double* __restrict__ stin,
                                              const float* __restrict__ gam, const float* __restrict__ bet,
                                              float Rin,
                                              OutT* __restrict__ out, double* __restrict__ stout) {
  constexpr int KK  = K / 32;
  constexpr int NT  = NOUT / 16;
  constexpr int UPR = K / 8;
  constexpr int LPR = UPR + 1;
  constexpr int LWB  = NOUT * LPR * 16;
  constexpr int ISCB = INACT ? 2 * K * 4 : 0;
  constexpr int SMB  = LWB + (ISCB > 0 ? ISCB : 1);
  __shared__ __align__(16) char smem[SMB];
  uint4* lw   = reinterpret_cast<uint4*>(smem);
  float* lsc  = reinterpret_cast<float*>(smem + LWB);
  float* lsh  = lsc + K;
  float* ssum = reinterpret_cast<float*>(smem);
  float* sqs  = ssum + 8 * NOUT;

  const uint4* wv = (const uint4*)Wt;
  for (int u = threadIdx.x; u < NOUT * UPR; u += 512) {
    int row = u / UPR, colu = u - row * UPR;
    lw[row * LPR + colu] = wv[u];
  }
  if (INACT) {
    for (int k = threadIdx.x; k < K; k += 512) {
      double mean = stin[k] / (double)Rin;
      double var  = stin[K + k] / (double)Rin - mean * mean;
      float sc = gam[k] * rsqrtf((float)var + 1e-5f);
      lsc[k] = sc;
      lsh[k] = bet[k] - (float)mean * sc;
    }
  }

  int wave = threadIdx.x >> 6, lane = threadIdx.x & 63;
  int m0 = (blockIdx.x * 8 + wave) * 16;
  int lr = lane & 15, lg = lane >> 4;

  short8v a[KK];
  if constexpr (AF32) {
    const float* Arow = (const float*)Aptr + (size_t)(m0 + lr) * K + lg * 8;
#pragma unroll
    for (int kk = 0; kk < KK; ++kk) {
      float4 f0 = *(const float4*)(Arow + kk * 32);
      float4 f1 = *(const float4*)(Arow + kk * 32 + 4);
      a[kk][0] = f2bfbits(f0.x); a[kk][1] = f2bfbits(f0.y);
      a[kk][2] = f2bfbits(f0.z); a[kk][3] = f2bfbits(f0.w);
      a[kk][4] = f2bfbits(f1.x); a[kk][5] = f2bfbits(f1.y);
      a[kk][6] = f2bfbits(f1.z); a[kk][7] = f2bfbits(f1.w);
    }
  } else {
    const short* Arow = (const short*)Aptr + (size_t)(m0 + lr) * K + lg * 8;
#pragma unroll
    for (int kk = 0; kk < KK; ++kk) a[kk] = *(const short8v*)(Arow + kk * 32);
  }

  __syncthreads();

  if (INACT) {
#pragma unroll
    for (int kk = 0; kk < KK; ++kk) {
      int kbase = kk * 32 + lg * 8;
#pragma unroll
      for (int j = 0; j < 8; ++j) {
        float f = bfbits2f(a[kk][j]);
        f = silu_f(fmaf(f, lsc[kbase + j], lsh[kbase + j]));
        a[kk][j] = f2bfbits(f);
      }
    }
  }

  f32x4 acc[NT];
#pragma unroll
  for (int nt = 0; nt < NT; ++nt) acc[nt] = (f32x4){0.f, 0.f, 0.f, 0.f};

#pragma unroll
  for (int nt = 0; nt < NT; ++nt) {
    const short* brow = (const short*)&lw[(nt * 16 + lr) * LPR] + lg * 8;
#pragma unroll
    for (int kk = 0; kk < KK; ++kk) {
      short8v b = *(const short8v*)(brow + kk * 32);
      acc[nt] = __builtin_amdgcn_mfma_f32_16x16x32_bf16(a[kk], b, acc[nt], 0, 0, 0);
    }
  }

  if (OSTATS) __syncthreads();

  int orow = m0 + (lg << 2);
#pragma unroll
  for (int nt = 0; nt < NT; ++nt) {
    int col = nt * 16 + lr;
    float bi = bias[col];
    float s = 0.f, q = 0.f;
#pragma unroll
    for (int r = 0; r < 4; ++r) {
      float y = acc[nt][r] + bi;
      float yb;
      size_t off = (size_t)(orow + r) * NOUT + col;
      if constexpr (sizeof(OutT) == 2) {
        short bits = f2bfbits(y);
        ((short*)out)[off] = bits;
        yb = bfbits2f(bits);
      } else {
        ((float*)out)[off] = y;
        yb = y;
      }
      if (OSTATS) { s += yb; q += yb * yb; }
    }
    if (OSTATS) {
      s += __shfl_xor(s, 16, 64); s += __shfl_xor(s, 32, 64);
      q += __shfl_xor(q, 16, 64); q += __shfl_xor(q, 32, 64);
      if (lg == 0) { ssum[wave * NOUT + col] = s; sqs[wave * NOUT + col] = q; }
    }
  }
  if (OSTATS) {
    __syncthreads();
    int tid = threadIdx.x;
    if (tid < NOUT) {
      float s = 0.f, q = 0.f;
#pragma unroll
      for (int w = 0; w < 8; ++w) { s += ssum[w * NOUT + tid]; q += sqs[w * NOUT + tid]; }
      atomAddD(&stout[tid], (double)s);
      atomAddD(&stout[NOUT + tid], (double)q);
    }
  }
}

// ===== fused aggregate + GEMM1 (+stats): wave-level WORK STEALING over 16-row items =========
// Grid sized to residency (768 blocks x 8 waves); each wave pulls items off a global counter.
// Items are LPT-ordered via perm (heavy-degree first); VN items (lightest) come last.
// Stats accumulate in a per-wave private LDS region (separate from the weight tile).
template <int K, int NOUT>   // K=96, NOUT=192
__global__ __launch_bounds__(512) void k_gemm_agg(const bf16* __restrict__ hb,
    const int* __restrict__ batch, const int* __restrict__ rs, const int* __restrict__ ssrc,
    const float* __restrict__ vna, const int* __restrict__ perm,
    const bf16* __restrict__ Wt, const float* __restrict__ bias,
    bf16* __restrict__ out, double* __restrict__ st, int* __restrict__ ctr) {
  constexpr int KK  = K / 32;
  constexpr int NT  = NOUT / 16;
  constexpr int UPR = K / 8;
  constexpr int LPR = UPR + 1;
  constexpr int LWB = NOUT * LPR * 16;   // 39936
  constexpr int STW = 8 * NOUT;          // per-array stat floats
  __shared__ __align__(16) char smem[LWB + 2 * STW * 4];   // 52224 B -> 3 blocks/CU
  uint4* lw    = reinterpret_cast<uint4*>(smem);
  float* lds_s = reinterpret_cast<float*>(smem + LWB);
  float* lds_q = lds_s + STW;

  const uint4* wv = (const uint4*)Wt;
  for (int u = threadIdx.x; u < NOUT * UPR; u += 512) {
    int row = u / UPR, colu = u - row * UPR;
    lw[row * LPR + colu] = wv[u];
  }
  for (int u = threadIdx.x; u < STW; u += 512) { lds_s[u] = 0.f; lds_q[u] = 0.f; }
  __syncthreads();

  int wave = threadIdx.x >> 6, lane = threadIdx.x & 63;
  int lr = lane & 15, lg = lane >> 4;
  int koff = lg * 8;

  auto hrow = [&](int r) { return (const short*)hb + (size_t)r * K; };

  for (;;) {
    int it;
    if (lane == 0) it = atomicAdd(ctr, 1);
    it = __shfl(it, 0, 64);
    if (it >= TOT_ / 16) break;

    int m0 = it * 16;
    int row = m0 + lr;
    int rowo = (m0 < N_) ? perm[row] : row;

    float av[KK * 8];
#pragma unroll
    for (int t = 0; t < KK * 8; ++t) av[t] = 0.f;

    auto addPtr = [&](const short* p) {
#pragma unroll
      for (int kk = 0; kk < KK; ++kk) {
        short8v v = *(const short8v*)(p + koff + kk * 32);
#pragma unroll
        for (int j = 0; j < 8; ++j) av[kk * 8 + j] += bfbits2f(v[j]);
      }
    };
    auto addPtr2 = [&](const short* p0, const short* p1) {
      short8v v0[KK], v1[KK];
#pragma unroll
      for (int kk = 0; kk < KK; ++kk) {
        v0[kk] = *(const short8v*)(p0 + koff + kk * 32);
        v1[kk] = *(const short8v*)(p1 + koff + kk * 32);
      }
#pragma unroll
      for (int kk = 0; kk < KK; ++kk)
#pragma unroll
        for (int j = 0; j < 8; ++j)
          av[kk * 8 + j] += bfbits2f(v0[kk][j]) + bfbits2f(v1[kk][j]);
    };

    if (m0 < N_) {
      addPtr2(hrow(rowo), hrow(N_ + batch[rowo]));
      int e = rs[rowo], e1 = rs[rowo + 1];
      for (; e + 2 <= e1; e += 2) addPtr2(hrow(ssrc[e]), hrow(ssrc[e + 1]));
      if (e < e1) addPtr(hrow(ssrc[e]));
    } else {
      addPtr(hrow(rowo));
      const float* vp = vna + (size_t)(rowo - N_) * K + koff;
#pragma unroll
      for (int kk = 0; kk < KK; ++kk) {
        float4 f0 = *(const float4*)(vp + kk * 32);
        float4 f1 = *(const float4*)(vp + kk * 32 + 4);
        av[kk * 8 + 0] += f0.x; av[kk * 8 + 1] += f0.y; av[kk * 8 + 2] += f0.z; av[kk * 8 + 3] += f0.w;
        av[kk * 8 + 4] += f1.x; av[kk * 8 + 5] += f1.y; av[kk * 8 + 6] += f1.z; av[kk * 8 + 7] += f1.w;
      }
    }

    short8v a[KK];
#pragma unroll
    for (int kk = 0; kk < KK; ++kk)
#pragma unroll
      for (int j = 0; j < 8; ++j) a[kk][j] = f2bfbits(av[kk * 8 + j]);

    f32x4 acc[NT];
#pragma unroll
    for (int nt = 0; nt < NT; ++nt) acc[nt] = (f32x4){0.f, 0.f, 0.f, 0.f};

#pragma unroll
    for (int nt = 0; nt < NT; ++nt) {
      const short* brow = (const short*)&lw[(nt * 16 + lr) * LPR] + lg * 8;
#pragma unroll
      for (int kk = 0; kk < KK; ++kk) {
        short8v b = *(const short8v*)(brow + kk * 32);
        acc[nt] = __builtin_amdgcn_mfma_f32_16x16x32_bf16(a[kk], b, acc[nt], 0, 0, 0);
      }
    }

    int rid[4];
#pragma unroll
    for (int r = 0; r < 4; ++r) rid[r] = __shfl(rowo, (lg << 2) + r, 64);

#pragma unroll
    for (int nt = 0; nt < NT; ++nt) {
      int col = nt * 16 + lr;
      float bi = bias[col];
      float s = 0.f, q = 0.f;
#pragma unroll
      for (int r = 0; r < 4; ++r) {
        float y = acc[nt][r] + bi;
        short bits = f2bfbits(y);
        ((short*)out)[(size_t)rid[r] * NOUT + col] = bits;
        float yb = bfbits2f(bits);
        s += yb; q += yb * yb;
      }
      s += __shfl_xor(s, 16, 64); s += __shfl_xor(s, 32, 64);
      q += __shfl_xor(q, 16, 64); q += __shfl_xor(q, 32, 64);
      if (lg == 0) {
        lds_s[wave * NOUT + col] += s;   // per-wave private region: no race
        lds_q[wave * NOUT + col] += q;
      }
    }
  }

  __syncthreads();
  int tid = threadIdx.x;
  if (tid < NOUT) {
    float s = 0.f, q = 0.f;
#pragma unroll
    for (int w = 0; w < 8; ++w) { s += lds_s[w * NOUT + tid]; q += lds_q[w * NOUT + tid]; }
    atomAddD(&st[tid], (double)s);
    atomAddD(&st[NOUT + tid], (double)q);
  }
}

__global__ __launch_bounds__(256) void k_fill_vn(bf16* __restrict__ hb, const float* __restrict__ vn) {
  int idx = blockIdx.x * 256 + threadIdx.x;
  if (idx >= G_ * C_) return;
  int c = idx % C_;
  hb[(size_t)N_ * C_ + idx] = __float2bfloat16(vn[c]);
}

template <int CC, typename T>
__global__ __launch_bounds__(256) void k_bnstats(const T* __restrict__ X, int R, double* __restrict__ st) {
  int c = threadIdx.x;
  float s = 0.f, q = 0.f;
  for (int r = blockIdx.x; r < R; r += gridDim.x) {
    float v = toF(X[(size_t)r * CC + c]);
    s += v;
    q += v * v;
  }
  atomAddD(&st[c], (double)s);
  atomAddD(&st[CC + c], (double)q);
}

template <int CC>
__global__ __launch_bounds__(256) void k_bnfin(const double* __restrict__ st, int R,
    const float* __restrict__ g, const float* __restrict__ be,
    float* __restrict__ scale, float* __restrict__ shift) {
  int c = threadIdx.x;
  if (c >= CC) return;
  double mean = st[c] / R;
  double var  = st[CC + c] / R - mean * mean;
  float sc = g[c] * rsqrtf((float)var + 1e-5f);
  scale[c] = sc;
  shift[c] = be[c] - (float)mean * sc;
}

// hb = (resid ? hb : 0) + silu(bn(Z)); 192 threads = 16 rows; fused per-graph vna accumulation
__global__ __launch_bounds__(192) void k_update(const bf16* __restrict__ Z, bf16* __restrict__ hb,
    const double* __restrict__ st,
    const float* __restrict__ gam, const float* __restrict__ bet, int addResid,
    float* __restrict__ vna, const int* __restrict__ batch, int accvna) {
  __shared__ float lsc[C_], lsh[C_];
  __shared__ float lh[16][C_];
  __shared__ int   lbatch[16];
  int t = threadIdx.x;
  if (t < C_) {
    double mean = st[t] / (double)TOT_;
    double var  = st[C_ + t] / (double)TOT_ - mean * mean;
    float sc = gam[t] * rsqrtf((float)var + 1e-5f);
    lsc[t] = sc;
    lsh[t] = bet[t] - (float)mean * sc;
  }
  int r0 = blockIdx.x * 16;
  int nodeBlk = (r0 < N_);            // N_ % 16 == 0: blocks never straddle
  if (accvna && nodeBlk && t < 16) lbatch[t] = batch[r0 + t];
  __syncthreads();

  int rl = t / 12;                    // 0..15
  int cg = t - rl * 12;               // 0..11
  int c0 = cg * 8;
  size_t vidx = (size_t)(r0 + rl) * 12 + cg;
  short8v zv = ((const short8v*)Z)[vidx];
  short8v hv = ((const short8v*)hb)[vidx];
  short8v o;
  float hn[8];
#pragma unroll
  for (int j = 0; j < 8; ++j) {
    float y = silu_f(fmaf(bfbits2f(zv[j]), lsc[c0 + j], lsh[c0 + j]));
    hn[j] = addResid ? (bfbits2f(hv[j]) + y) : y;
    o[j] = f2bfbits(hn[j]);
  }
  ((short8v*)hb)[vidx] = o;

  if (accvna && nodeBlk) {
#pragma unroll
    for (int j = 0; j < 8; ++j) lh[rl][c0 + j] = hn[j];
    __syncthreads();
    if (t < C_) {
      int c = t;
      float run = 0.f;
      int g = lbatch[0];
      for (int r = 0; r < 16; ++r) {
        int gb = lbatch[r];
        if (gb != g) { atomAddF(&vna[(size_t)g * C_ + c], run); run = 0.f; g = gb; }
        run += lh[r][c];
      }
      atomAddF(&vna[(size_t)g * C_ + c], run);
    }
  }
}

template <int K, int M, bool INACT>
__global__ __launch_bounds__(256) void k_mm(const float* __restrict__ A,
    const float* __restrict__ W, const float* __restrict__ bias,
    const float* __restrict__ isc, const float* __restrict__ ish,
    float* __restrict__ out, int R) {
  int idx = blockIdx.x * 256 + threadIdx.x;
  if (idx >= R * M) return;
  int row = idx / M;
  int m   = idx - row * M;
  const float* ar = A + (size_t)row * K;
  float s = bias[m];
#pragma unroll 8
  for (int k = 0; k < K; ++k) {
    float a = ar[k];
    if (INACT) a = silu_f(fmaf(a, isc[k], ish[k]));
    s = fmaf(a, W[k * M + m], s);
  }
  out[idx] = s;
}

__global__ __launch_bounds__(256) void k_pool2(const bf16* __restrict__ hb, const int* __restrict__ gstart,
                                               float* __restrict__ pooled) {
  int idx = blockIdx.x * 256 + threadIdx.x;
  if (idx >= G_ * C_) return;
  int g = idx / C_;
  int c = idx - g * C_;
  int i0 = gstart[g], i1 = gstart[g + 1];
  float s = 0.f;
  for (int i = i0; i < i1; ++i) s += toF(hb[(size_t)i * C_ + c]);
  pooled[idx] = s / fmaxf((float)(i1 - i0), 1.0f);
}

extern "C" void kernel_launch(void* const* d_in, const int* in_sizes, int n_in,
                              void* d_out, int out_size, void* d_ws, size_t ws_size,
                              hipStream_t stream) {
  (void)in_sizes; (void)n_in; (void)out_size; (void)ws_size;
  const float* x       = (const float*)d_in[0];
  const int*   ei      = (const int*)d_in[1];
  const int*   batch   = (const int*)d_in[2];
  const float* enc_w   = (const float*)d_in[4];
  const float* enc_b   = (const float*)d_in[5];
  const float* vn_emb  = (const float*)d_in[6];
  const float* vn_w1   = (const float*)d_in[7];
  const float* vn_b1   = (const float*)d_in[8];
  const float* vn_g1   = (const float*)d_in[9];
  const float* vn_be1  = (const float*)d_in[10];
  const float* vn_w2   = (const float*)d_in[11];
  const float* vn_b2   = (const float*)d_in[12];
  const float* conv_w1 = (const float*)d_in[13];
  const float* conv_b1 = (const float*)d_in[14];
  const float* conv_g1 = (const float*)d_in[15];
  const float* conv_be1= (const float*)d_in[16];
  const float* conv_w2 = (const float*)d_in[17];
  const float* conv_b2 = (const float*)d_in[18];
  const float* bn_g    = (const float*)d_in[19];
  const float* bn_b    = (const float*)d_in[20];
  const float* h_w1    = (const float*)d_in[21];
  const float* h_b1    = (const float*)d_in[22];
  const float* h_g1    = (const float*)d_in[23];
  const float* h_be1   = (const float*)d_in[24];
  const float* h_w2    = (const float*)d_in[25];
  const float* h_b2    = (const float*)d_in[26];
  const float* h_g2    = (const float*)d_in[27];
  const float* h_be2   = (const float*)d_in[28];
  const float* h_w3    = (const float*)d_in[29];
  const float* h_b3    = (const float*)d_in[30];
  float* out = (float*)d_out;

  const int* e_src = ei;
  const int* e_tgt = ei + E_;

  char* p = (char*)d_ws;
  auto alloc = [&](size_t bytes) -> char* {
    char* r = p;
    p += (bytes + 15) & ~size_t(15);
    return r;
  };
  bf16*   hbf    = (bf16*)  alloc((size_t)TOT_ * C_ * 2);
  float*  vnaf   = (float*) alloc((size_t)G_ * C_ * 4);
  bf16*   vtb    = (bf16*)  alloc((size_t)G_ * C_ * 2);
  float*  pooled = (float*) alloc((size_t)G_ * C_ * 4);
  float*  t1     = (float*) alloc((size_t)G_ * 48 * 4);
  float*  t2     = (float*) alloc((size_t)G_ * 24 * 4);
  float*  scale1 = (float*) alloc(256 * 4);
  float*  shift1 = (float*) alloc(256 * 4);
  float*  scale2 = (float*) alloc(256 * 4);
  float*  shift2 = (float*) alloc(256 * 4);
  double* stbuf  = (double*)alloc((size_t)26 * 384 * 8);
  bf16*   z1     = (bf16*)  alloc((size_t)TOT_ * 2 * C_ * 2);
  bf16*   z2     = (bf16*)  alloc((size_t)TOT_ * C_ * 2);
  bf16*   encwT  = (bf16*)  alloc((size_t)C_ * FIN_ * 2);
  bf16*   w1T    = (bf16*)  alloc((size_t)L_ * 2 * C_ * C_ * 2);
  bf16*   w2T    = (bf16*)  alloc((size_t)L_ * C_ * 2 * C_ * 2);
  bf16*   vnw1T  = (bf16*)  alloc((size_t)C_ * C_ * 2);
  bf16*   vnw2T  = (bf16*)  alloc((size_t)C_ * C_ * 2);
  int*    deg    = (int*)   alloc((size_t)N_ * 4);
  int*    cur    = (int*)   alloc((size_t)N_ * 4);
  int*    rs     = (int*)   alloc((size_t)(N_ + 1) * 4);
  int*    bsum   = (int*)   alloc(512 * 4);
  int*    boff   = (int*)   alloc(512 * 4);
  int*    ssrc   = (int*)   alloc((size_t)E_ * 4);
  int*    gstart = (int*)   alloc((size_t)(G_ + 1) * 4);
  int*    perm   = (int*)   alloc((size_t)N_ * 4);
  int*    hist   = (int*)   alloc(33 * 4);
  int*    hbase  = (int*)   alloc(33 * 4);
  int*    hcurs  = (int*)   alloc(33 * 4);
  int*    aggctr = (int*)   alloc(32 * 4);   // per-layer steal counters

  auto ST = [&](int i) { return stbuf + (size_t)i * 384; };

  // ---- preprocessing ----
  k_prep<<<gblk(319488), 256, 0, stream>>>(enc_w, conv_w1, conv_w2, vn_w1, vn_w2,
                                           encwT, w1T, w2T, vnw1T, vnw2T);

  hipMemsetAsync(deg, 0, (size_t)N_ * 4, stream);
  hipMemsetAsync(cur, 0, (size_t)N_ * 4, stream);
  hipMemsetAsync(stbuf, 0, (size_t)26 * 384 * 8, stream);
  hipMemsetAsync(hist, 0, 33 * 4, stream);
  hipMemsetAsync(hcurs, 0, 33 * 4, stream);
  hipMemsetAsync(aggctr, 0, 32 * 4, stream);
  k_deg_count<<<gblk(E_), 256, 0, stream>>>(e_tgt, deg);
  k_scan_local<<<N_ / 256, 256, 0, stream>>>(deg, rs, bsum);
  k_scan_bsum<<<1, 512, 0, stream>>>(bsum, boff);
  k_scan_add<<<gblk(N_ + 1), 256, 0, stream>>>(rs, boff);
  k_csr_fill<<<gblk(E_), 256, 0, stream>>>(e_src, e_tgt, rs, cur, ssrc);
  k_gbounds<<<gblk(N_ + 1), 256, 0, stream>>>(batch, gstart);
  k_deghist<<<gblk(N_), 256, 0, stream>>>(deg, hist);
  k_degbase<<<1, 64, 0, stream>>>(hist, hbase);
  k_permfill<<<gblk(N_), 256, 0, stream>>>(deg, hbase, hcurs, perm);

  // ---- encoder + VN init ----
  k_gemm<FIN_, C_, false, false, true, bf16><<<N_ / 128, 512, 0, stream>>>(
      x, encwT, enc_b, nullptr, nullptr, nullptr, 1.f, hbf, nullptr);
  k_fill_vn<<<gblk((long)G_ * C_), 256, 0, stream>>>(hbf, vn_emb);
  k_vnagg<<<G_ / 8, 192, 0, stream>>>(hbf, gstart, vnaf);

  // ---- 8 conv layers ----
  for (int i = 0; i < L_; ++i) {
    const bf16*  wt1 = w1T + (size_t)i * 2 * C_ * C_;
    const bf16*  wt2 = w2T + (size_t)i * C_ * 2 * C_;
    const float* b1  = conv_b1 + (size_t)i * 2 * C_;
    const float* g1  = conv_g1 + (size_t)i * 2 * C_;
    const float* be1 = conv_be1+ (size_t)i * 2 * C_;
    const float* b2  = conv_b2 + (size_t)i * C_;
    const float* bg  = bn_g    + (size_t)i * C_;
    const float* bb  = bn_b    + (size_t)i * C_;
    int accvna = (i < L_ - 1);

    k_gemm_agg<C_, 2 * C_><<<768, 512, 0, stream>>>(
        hbf, batch, rs, ssrc, vnaf, perm, wt1, b1, z1, ST(i), aggctr + i);

    k_gemm<2 * C_, C_, true, true, false, bf16><<<TOT_ / 128, 512, 0, stream>>>(
        z1, wt2, b2, ST(i), g1, be1, (float)TOT_, z2, ST(8 + i));

    if (accvna) hipMemsetAsync(vnaf, 0, (size_t)G_ * C_ * 4, stream);
    k_update<<<TOT_ / 16, 192, 0, stream>>>(z2, hbf, ST(8 + i), bg, bb, i > 0,
                                            vnaf, batch, accvna);

    if (i < L_ - 1) {
      k_gemm<C_, C_, false, true, false, bf16><<<G_ / 128, 512, 0, stream>>>(
          hbf + (size_t)N_ * C_, vnw1T, vn_b1, nullptr, nullptr, nullptr, 1.f, vtb, ST(16 + i));
      k_gemm<C_, C_, true, false, false, bf16><<<G_ / 128, 512, 0, stream>>>(
          vtb, vnw2T, vn_b2, ST(16 + i), vn_g1, vn_be1, (float)G_,
          hbf + (size_t)N_ * C_, nullptr);
    }
  }

  // ---- mean pool ----
  k_pool2<<<gblk((long)G_ * C_), 256, 0, stream>>>(hbf, gstart, pooled);

  // ---- head MLP ----
  k_mm<C_, 48, false><<<gblk((long)G_ * 48), 256, 0, stream>>>(
      pooled, h_w1, h_b1, nullptr, nullptr, t1, G_);
  k_bnstats<48, float><<<64, 48, 0, stream>>>(t1, G_, ST(23));
  k_bnfin<48><<<1, 48, 0, stream>>>(ST(23), G_, h_g1, h_be1, scale1, shift1);

  k_mm<48, 24, true><<<gblk((long)G_ * 24), 256, 0, stream>>>(
      t1, h_w2, h_b2, scale1, shift1, t2, G_);
  k_bnstats<24, float><<<64, 24, 0, stream>>>(t2, G_, ST(24));
  k_bnfin<24><<<1, 24, 0, stream>>>(ST(24), G_, h_g2, h_be2, scale2, shift2);

  k_mm<24, 5, true><<<gblk((long)G_ * 5), 256, 0, stream>>>(
      t2, h_w3, h_b3, scale2, shift2, out, G_);
}

// Round 18
// 1161.914 us; speedup vs baseline: 1.8822x; 1.8818x over previous
//
#include <hip/hip_runtime.h>
#include <hip/hip_bf16.h>

constexpr int N_   = 131072;
constexpr int G_   = 4096;
constexpr int E_   = 524288;
constexpr int C_   = 96;
constexpr int L_   = 8;
constexpr int FIN_ = 64;
constexpr int TOT_ = N_ + G_;   // 135168 (divisible by 128; N_ divisible by 16)

typedef __attribute__((ext_vector_type(8))) short short8v;
typedef __attribute__((ext_vector_type(4))) float f32x4;
using bf16 = __hip_bfloat16;

__device__ __forceinline__ float silu_f(float y) { return y / (1.f + __expf(-y)); }
__device__ __forceinline__ float toF(float x) { return x; }
__device__ __forceinline__ float toF(bf16 x)  { return __bfloat162float(x); }
__device__ __forceinline__ float bfbits2f(short s) {
  return __uint_as_float(((unsigned)(unsigned short)s) << 16);
}
__device__ __forceinline__ short f2bfbits(float f) {
  bf16 b = __float2bfloat16(f);
  return *reinterpret_cast<short*>(&b);
}
__device__ __forceinline__ void atomAddD(double* p, double v) { unsafeAtomicAdd(p, v); }
__device__ __forceinline__ void atomAddF(float* p, float v)  { unsafeAtomicAdd(p, v); }

static inline int gblk(long n) { return (int)((n + 255) / 256); }

// ======================= preprocessing (all weight transposes fused) =======================
__global__ __launch_bounds__(256) void k_prep(const float* __restrict__ enc_w,
    const float* __restrict__ conv_w1, const float* __restrict__ conv_w2,
    const float* __restrict__ vn_w1, const float* __restrict__ vn_w2,
    bf16* __restrict__ encwT, bf16* __restrict__ w1T, bf16* __restrict__ w2T,
    bf16* __restrict__ vnw1T, bf16* __restrict__ vnw2T) {
  int idx = blockIdx.x * 256 + threadIdx.x;
  const float* src; bf16* dst; int Kd, Nd, local;
  if (idx < 6144)        { src = enc_w;   dst = encwT; Kd = 64;  Nd = 96;  local = idx; }
  else if (idx < 153600) { src = conv_w1; dst = w1T;   Kd = 96;  Nd = 192; local = idx - 6144; }
  else if (idx < 301056) { src = conv_w2; dst = w2T;   Kd = 192; Nd = 96;  local = idx - 153600; }
  else if (idx < 310272) { src = vn_w1;   dst = vnw1T; Kd = 96;  Nd = 96;  local = idx - 301056; }
  else if (idx < 319488) { src = vn_w2;   dst = vnw2T; Kd = 96;  Nd = 96;  local = idx - 310272; }
  else return;
  int per = Kd * Nd;
  int i   = local / per;
  int rem = local - i * per;
  int k   = rem / Nd;
  int n   = rem - k * Nd;
  dst[(size_t)i * per + n * Kd + k] = __float2bfloat16(src[local]);
}

__global__ __launch_bounds__(256) void k_deg_count(const int* __restrict__ tgt, int* __restrict__ deg) {
  int e = blockIdx.x * 256 + threadIdx.x;
  if (e >= E_) return;
  atomicAdd(&deg[tgt[e]], 1);
}

__global__ __launch_bounds__(256) void k_scan_local(const int* __restrict__ deg, int* __restrict__ lp,
                                                    int* __restrict__ bsum) {
  __shared__ int s[256];
  int t = threadIdx.x;
  int i = blockIdx.x * 256 + t;
  int v = deg[i];
  s[t] = v;
  __syncthreads();
  for (int off = 1; off < 256; off <<= 1) {
    int x = (t >= off) ? s[t - off] : 0;
    __syncthreads();
    s[t] += x;
    __syncthreads();
  }
  lp[i] = s[t] - v;
  if (t == 255) bsum[blockIdx.x] = s[255];
}

__global__ __launch_bounds__(512) void k_scan_bsum(const int* __restrict__ bsum, int* __restrict__ boff) {
  __shared__ int s[512];
  int t = threadIdx.x;
  int v = bsum[t];
  s[t] = v;
  __syncthreads();
  for (int off = 1; off < 512; off <<= 1) {
    int x = (t >= off) ? s[t - off] : 0;
    __syncthreads();
    s[t] += x;
    __syncthreads();
  }
  boff[t] = s[t] - v;
}

__global__ __launch_bounds__(256) void k_scan_add(int* __restrict__ rs, const int* __restrict__ boff) {
  int i = blockIdx.x * 256 + threadIdx.x;
  if (i > N_) return;
  if (i == N_) { rs[N_] = E_; return; }
  rs[i] += boff[i >> 8];
}

__global__ __launch_bounds__(256) void k_csr_fill(const int* __restrict__ src, const int* __restrict__ tgt,
                                                  const int* __restrict__ rs, int* __restrict__ cur,
                                                  int* __restrict__ ssrc) {
  int e = blockIdx.x * 256 + threadIdx.x;
  if (e >= E_) return;
  int t = tgt[e];
  int pos = atomicAdd(&cur[t], 1);
  ssrc[rs[t] + pos] = src[e];
}

__global__ __launch_bounds__(256) void k_gbounds(const int* __restrict__ batch, int* __restrict__ gstart) {
  int i = blockIdx.x * 256 + threadIdx.x;
  if (i > N_) return;
  if (i == N_) {
    int last = batch[N_ - 1];
    for (int g = last + 1; g <= G_; ++g) gstart[g] = N_;
    return;
  }
  int b  = batch[i];
  int bp = (i == 0) ? -1 : batch[i - 1];
  for (int g = bp + 1; g <= b; ++g) gstart[g] = i;
}

// ---- degree-balanced permutation (two-level histogram; LPT: heaviest buckets FIRST) ----
__global__ __launch_bounds__(256) void k_deghist(const int* __restrict__ deg, int* __restrict__ hist) {
  __shared__ int lh[33];
  if (threadIdx.x < 33) lh[threadIdx.x] = 0;
  __syncthreads();
  int i = blockIdx.x * 256 + threadIdx.x;
  if (i < N_) {
    int b = deg[i]; if (b > 32) b = 32;
    atomicAdd(&lh[b], 1);
  }
  __syncthreads();
  if (threadIdx.x < 33 && lh[threadIdx.x] != 0) atomicAdd(&hist[threadIdx.x], lh[threadIdx.x]);
}

__global__ __launch_bounds__(64) void k_degbase(const int* __restrict__ hist, int* __restrict__ base) {
  if (threadIdx.x == 0) {
    int acc = 0;
    for (int b = 32; b >= 0; --b) { base[b] = acc; acc += hist[b]; }   // descending: LPT
  }
}

__global__ __launch_bounds__(256) void k_permfill(const int* __restrict__ deg, const int* __restrict__ base,
                                                  int* __restrict__ curs, int* __restrict__ perm) {
  __shared__ int lh[33];
  __shared__ int lbase[33];
  if (threadIdx.x < 33) lh[threadIdx.x] = 0;
  __syncthreads();
  int i = blockIdx.x * 256 + threadIdx.x;
  int b = 0, lpos = 0;
  bool act = (i < N_);
  if (act) {
    b = deg[i]; if (b > 32) b = 32;
    lpos = atomicAdd(&lh[b], 1);
  }
  __syncthreads();
  if (threadIdx.x < 33) {
    int cnt = lh[threadIdx.x];
    lbase[threadIdx.x] = cnt ? atomicAdd(&curs[threadIdx.x], cnt) : 0;
  }
  __syncthreads();
  if (act) perm[base[b] + lbase[b] + lpos] = i;
}

// layer-0 per-graph segment sum of hbf -> vna (fp32)
__global__ __launch_bounds__(192) void k_vnagg(const bf16* __restrict__ hb, const int* __restrict__ gstart,
                                               float* __restrict__ vna) {
  int slot = threadIdx.x / 24;
  int c4   = (threadIdx.x % 24) * 4;
  int g = blockIdx.x * 8 + slot;
  int i0 = gstart[g], i1 = gstart[g + 1];
  float s0 = 0.f, s1 = 0.f, s2 = 0.f, s3 = 0.f;
  for (int i = i0; i < i1; ++i) {
    short4 v = *(const short4*)((const short*)hb + (size_t)i * C_ + c4);
    s0 += bfbits2f(v.x); s1 += bfbits2f(v.y); s2 += bfbits2f(v.z); s3 += bfbits2f(v.w);
  }
  float4 o; o.x = s0; o.y = s1; o.z = s2; o.w = s3;
  *(float4*)(vna + (size_t)g * C_ + c4) = o;
}

// ======================= MFMA GEMM, 512 threads =======================
template <int K, int NOUT, bool INACT, bool OSTATS, bool AF32, typename OutT>
__global__ __launch_bounds__(512) void k_gemm(const void* __restrict__ Aptr, const bf16* __restrict__ Wt,
                                              const float* __restrict__ bias,
                                              const double* __restrict__ stin,
                                              const float* __restrict__ gam, const float* __restrict__ bet,
                                              float Rin,
                                              OutT* __restrict__ out, double* __restrict__ stout) {
  constexpr int KK  = K / 32;
  constexpr int NT  = NOUT / 16;
  constexpr int UPR = K / 8;
  constexpr int LPR = UPR + 1;
  constexpr int LWB  = NOUT * LPR * 16;
  constexpr int ISCB = INACT ? 2 * K * 4 : 0;
  constexpr int SMB  = LWB + (ISCB > 0 ? ISCB : 1);
  __shared__ __align__(16) char smem[SMB];
  uint4* lw   = reinterpret_cast<uint4*>(smem);
  float* lsc  = reinterpret_cast<float*>(smem + LWB);
  float* lsh  = lsc + K;
  float* ssum = reinterpret_cast<float*>(smem);
  float* sqs  = ssum + 8 * NOUT;

  const uint4* wv = (const uint4*)Wt;
  for (int u = threadIdx.x; u < NOUT * UPR; u += 512) {
    int row = u / UPR, colu = u - row * UPR;
    lw[row * LPR + colu] = wv[u];
  }
  if (INACT) {
    for (int k = threadIdx.x; k < K; k += 512) {
      double mean = stin[k] / (double)Rin;
      double var  = stin[K + k] / (double)Rin - mean * mean;
      float sc = gam[k] * rsqrtf((float)var + 1e-5f);
      lsc[k] = sc;
      lsh[k] = bet[k] - (float)mean * sc;
    }
  }

  int wave = threadIdx.x >> 6, lane = threadIdx.x & 63;
  int m0 = (blockIdx.x * 8 + wave) * 16;
  int lr = lane & 15, lg = lane >> 4;

  short8v a[KK];
  if constexpr (AF32) {
    const float* Arow = (const float*)Aptr + (size_t)(m0 + lr) * K + lg * 8;
#pragma unroll
    for (int kk = 0; kk < KK; ++kk) {
      float4 f0 = *(const float4*)(Arow + kk * 32);
      float4 f1 = *(const float4*)(Arow + kk * 32 + 4);
      a[kk][0] = f2bfbits(f0.x); a[kk][1] = f2bfbits(f0.y);
      a[kk][2] = f2bfbits(f0.z); a[kk][3] = f2bfbits(f0.w);
      a[kk][4] = f2bfbits(f1.x); a[kk][5] = f2bfbits(f1.y);
      a[kk][6] = f2bfbits(f1.z); a[kk][7] = f2bfbits(f1.w);
    }
  } else {
    const short* Arow = (const short*)Aptr + (size_t)(m0 + lr) * K + lg * 8;
#pragma unroll
    for (int kk = 0; kk < KK; ++kk) a[kk] = *(const short8v*)(Arow + kk * 32);
  }

  __syncthreads();

  if (INACT) {
#pragma unroll
    for (int kk = 0; kk < KK; ++kk) {
      int kbase = kk * 32 + lg * 8;
#pragma unroll
      for (int j = 0; j < 8; ++j) {
        float f = bfbits2f(a[kk][j]);
        f = silu_f(fmaf(f, lsc[kbase + j], lsh[kbase + j]));
        a[kk][j] = f2bfbits(f);
      }
    }
  }

  f32x4 acc[NT];
#pragma unroll
  for (int nt = 0; nt < NT; ++nt) acc[nt] = (f32x4){0.f, 0.f, 0.f, 0.f};

#pragma unroll
  for (int nt = 0; nt < NT; ++nt) {
    const short* brow = (const short*)&lw[(nt * 16 + lr) * LPR] + lg * 8;
#pragma unroll
    for (int kk = 0; kk < KK; ++kk) {
      short8v b = *(const short8v*)(brow + kk * 32);
      acc[nt] = __builtin_amdgcn_mfma_f32_16x16x32_bf16(a[kk], b, acc[nt], 0, 0, 0);
    }
  }

  if (OSTATS) __syncthreads();

  int orow = m0 + (lg << 2);
#pragma unroll
  for (int nt = 0; nt < NT; ++nt) {
    int col = nt * 16 + lr;
    float bi = bias[col];
    float s = 0.f, q = 0.f;
#pragma unroll
    for (int r = 0; r < 4; ++r) {
      float y = acc[nt][r] + bi;
      float yb;
      size_t off = (size_t)(orow + r) * NOUT + col;
      if constexpr (sizeof(OutT) == 2) {
        short bits = f2bfbits(y);
        ((short*)out)[off] = bits;
        yb = bfbits2f(bits);
      } else {
        ((float*)out)[off] = y;
        yb = y;
      }
      if (OSTATS) { s += yb; q += yb * yb; }
    }
    if (OSTATS) {
      s += __shfl_xor(s, 16, 64); s += __shfl_xor(s, 32, 64);
      q += __shfl_xor(q, 16, 64); q += __shfl_xor(q, 32, 64);
      if (lg == 0) { ssum[wave * NOUT + col] = s; sqs[wave * NOUT + col] = q; }
    }
  }
  if (OSTATS) {
    __syncthreads();
    int tid = threadIdx.x;
    if (tid < NOUT) {
      float s = 0.f, q = 0.f;
#pragma unroll
      for (int w = 0; w < 8; ++w) { s += ssum[w * NOUT + tid]; q += sqs[w * NOUT + tid]; }
      atomAddD(&stout[tid], (double)s);
      atomAddD(&stout[NOUT + tid], (double)q);
    }
  }
}

// ======= fused aggregate + GEMM1 (+stats), 512 threads, LPT-permuted rows, fp32 vna ==========
template <int K, int NOUT>   // K=96, NOUT=192
__global__ __launch_bounds__(512) void k_gemm_agg(const bf16* __restrict__ hb,
    const int* __restrict__ batch, const int* __restrict__ rs, const int* __restrict__ ssrc,
    const float* __restrict__ vna, const int* __restrict__ perm,
    const bf16* __restrict__ Wt, const float* __restrict__ bias,
    bf16* __restrict__ out, double* __restrict__ st) {
  constexpr int KK  = K / 32;
  constexpr int NT  = NOUT / 16;
  constexpr int UPR = K / 8;
  constexpr int LPR = UPR + 1;
  constexpr int LWB = NOUT * LPR * 16;   // 39936
  __shared__ __align__(16) char smem[LWB];
  uint4* lw   = reinterpret_cast<uint4*>(smem);
  float* ssum = reinterpret_cast<float*>(smem);
  float* sqs  = ssum + 8 * NOUT;

  const uint4* wv = (const uint4*)Wt;
  for (int u = threadIdx.x; u < NOUT * UPR; u += 512) {
    int row = u / UPR, colu = u - row * UPR;
    lw[row * LPR + colu] = wv[u];
  }
  // no barrier yet — register gather below doesn't touch LDS

  int wave = threadIdx.x >> 6, lane = threadIdx.x & 63;
  int m0 = (blockIdx.x * 8 + wave) * 16;
  int lr = lane & 15, lg = lane >> 4;
  int row = m0 + lr;
  int rowo = (m0 < N_) ? perm[row] : row;
  int koff = lg * 8;

  float av[KK * 8];
#pragma unroll
  for (int t = 0; t < KK * 8; ++t) av[t] = 0.f;

  auto addPtr = [&](const short* p) {
#pragma unroll
    for (int kk = 0; kk < KK; ++kk) {
      short8v v = *(const short8v*)(p + koff + kk * 32);
#pragma unroll
      for (int j = 0; j < 8; ++j) av[kk * 8 + j] += bfbits2f(v[j]);
    }
  };
  auto addPtr2 = [&](const short* p0, const short* p1) {
    short8v v0[KK], v1[KK];
#pragma unroll
    for (int kk = 0; kk < KK; ++kk) {
      v0[kk] = *(const short8v*)(p0 + koff + kk * 32);
      v1[kk] = *(const short8v*)(p1 + koff + kk * 32);
    }
#pragma unroll
    for (int kk = 0; kk < KK; ++kk)
#pragma unroll
      for (int j = 0; j < 8; ++j)
        av[kk * 8 + j] += bfbits2f(v0[kk][j]) + bfbits2f(v1[kk][j]);
  };
  auto hrow = [&](int r) { return (const short*)hb + (size_t)r * K; };

  if (m0 < N_) {
    addPtr2(hrow(rowo), hrow(N_ + batch[rowo]));
    int e = rs[rowo], e1 = rs[rowo + 1];
    for (; e + 2 <= e1; e += 2) addPtr2(hrow(ssrc[e]), hrow(ssrc[e + 1]));
    if (e < e1) addPtr(hrow(ssrc[e]));
  } else {
    addPtr(hrow(rowo));
    const float* vp = vna + (size_t)(rowo - N_) * K + koff;
#pragma unroll
    for (int kk = 0; kk < KK; ++kk) {
      float4 f0 = *(const float4*)(vp + kk * 32);
      float4 f1 = *(const float4*)(vp + kk * 32 + 4);
      av[kk * 8 + 0] += f0.x; av[kk * 8 + 1] += f0.y; av[kk * 8 + 2] += f0.z; av[kk * 8 + 3] += f0.w;
      av[kk * 8 + 4] += f1.x; av[kk * 8 + 5] += f1.y; av[kk * 8 + 6] += f1.z; av[kk * 8 + 7] += f1.w;
    }
  }

  short8v a[KK];
#pragma unroll
  for (int kk = 0; kk < KK; ++kk)
#pragma unroll
    for (int j = 0; j < 8; ++j) a[kk][j] = f2bfbits(av[kk * 8 + j]);

  __syncthreads();   // weights ready

  f32x4 acc[NT];
#pragma unroll
  for (int nt = 0; nt < NT; ++nt) acc[nt] = (f32x4){0.f, 0.f, 0.f, 0.f};

#pragma unroll
  for (int nt = 0; nt < NT; ++nt) {
    const short* brow = (const short*)&lw[(nt * 16 + lr) * LPR] + lg * 8;
#pragma unroll
    for (int kk = 0; kk < KK; ++kk) {
      short8v b = *(const short8v*)(brow + kk * 32);
      acc[nt] = __builtin_amdgcn_mfma_f32_16x16x32_bf16(a[kk], b, acc[nt], 0, 0, 0);
    }
  }

  __syncthreads();   // weights dead; stats overlay

  int rid[4];
#pragma unroll
  for (int r = 0; r < 4; ++r) rid[r] = __shfl(rowo, (lg << 2) + r, 64);

#pragma unroll
  for (int nt = 0; nt < NT; ++nt) {
    int col = nt * 16 + lr;
    float bi = bias[col];
    float s = 0.f, q = 0.f;
#pragma unroll
    for (int r = 0; r < 4; ++r) {
      float y = acc[nt][r] + bi;
      short bits = f2bfbits(y);
      ((short*)out)[(size_t)rid[r] * NOUT + col] = bits;
      float yb = bfbits2f(bits);
      s += yb; q += yb * yb;
    }
    s += __shfl_xor(s, 16, 64); s += __shfl_xor(s, 32, 64);
    q += __shfl_xor(q, 16, 64); q += __shfl_xor(q, 32, 64);
    if (lg == 0) { ssum[wave * NOUT + col] = s; sqs[wave * NOUT + col] = q; }
  }
  __syncthreads();
  int tid = threadIdx.x;
  if (tid < NOUT) {
    float s = 0.f, q = 0.f;
#pragma unroll
    for (int w = 0; w < 8; ++w) { s += ssum[w * NOUT + tid]; q += sqs[w * NOUT + tid]; }
    atomAddD(&st[tid], (double)s);
    atomAddD(&st[NOUT + tid], (double)q);
  }
}

__global__ __launch_bounds__(256) void k_fill_vn(bf16* __restrict__ hb, const float* __restrict__ vn) {
  int idx = blockIdx.x * 256 + threadIdx.x;
  if (idx >= G_ * C_) return;
  int c = idx % C_;
  hb[(size_t)N_ * C_ + idx] = __float2bfloat16(vn[c]);
}

template <int CC, typename T>
__global__ __launch_bounds__(256) void k_bnstats(const T* __restrict__ X, int R, double* __restrict__ st) {
  int c = threadIdx.x;
  float s = 0.f, q = 0.f;
  for (int r = blockIdx.x; r < R; r += gridDim.x) {
    float v = toF(X[(size_t)r * CC + c]);
    s += v;
    q += v * v;
  }
  atomAddD(&st[c], (double)s);
  atomAddD(&st[CC + c], (double)q);
}

template <int CC>
__global__ __launch_bounds__(256) void k_bnfin(const double* __restrict__ st, int R,
    const float* __restrict__ g, const float* __restrict__ be,
    float* __restrict__ scale, float* __restrict__ shift) {
  int c = threadIdx.x;
  if (c >= CC) return;
  double mean = st[c] / R;
  double var  = st[CC + c] / R - mean * mean;
  float sc = g[c] * rsqrtf((float)var + 1e-5f);
  scale[c] = sc;
  shift[c] = be[c] - (float)mean * sc;
}

// hb = (resid ? hb : 0) + silu(bn(Z)); 192 threads = 16 rows; fused per-graph vna accumulation
__global__ __launch_bounds__(192) void k_update(const bf16* __restrict__ Z, bf16* __restrict__ hb,
    const double* __restrict__ st,
    const float* __restrict__ gam, const float* __restrict__ bet, int addResid,
    float* __restrict__ vna, const int* __restrict__ batch, int accvna) {
  __shared__ float lsc[C_], lsh[C_];
  __shared__ float lh[16][C_];
  __shared__ int   lbatch[16];
  int t = threadIdx.x;
  if (t < C_) {
    double mean = st[t] / (double)TOT_;
    double var  = st[C_ + t] / (double)TOT_ - mean * mean;
    float sc = gam[t] * rsqrtf((float)var + 1e-5f);
    lsc[t] = sc;
    lsh[t] = bet[t] - (float)mean * sc;
  }
  int r0 = blockIdx.x * 16;
  int nodeBlk = (r0 < N_);            // N_ % 16 == 0: blocks never straddle
  if (accvna && nodeBlk && t < 16) lbatch[t] = batch[r0 + t];
  __syncthreads();

  int rl = t / 12;                    // 0..15
  int cg = t - rl * 12;               // 0..11
  int c0 = cg * 8;
  size_t vidx = (size_t)(r0 + rl) * 12 + cg;
  short8v zv = ((const short8v*)Z)[vidx];
  short8v hv = ((const short8v*)hb)[vidx];
  short8v o;
  float hn[8];
#pragma unroll
  for (int j = 0; j < 8; ++j) {
    float y = silu_f(fmaf(bfbits2f(zv[j]), lsc[c0 + j], lsh[c0 + j]));
    hn[j] = addResid ? (bfbits2f(hv[j]) + y) : y;
    o[j] = f2bfbits(hn[j]);
  }
  ((short8v*)hb)[vidx] = o;

  if (accvna && nodeBlk) {
#pragma unroll
    for (int j = 0; j < 8; ++j) lh[rl][c0 + j] = hn[j];
    __syncthreads();
    if (t < C_) {
      int c = t;
      float run = 0.f;
      int g = lbatch[0];
      for (int r = 0; r < 16; ++r) {
        int gb = lbatch[r];
        if (gb != g) { atomAddF(&vna[(size_t)g * C_ + c], run); run = 0.f; g = gb; }
        run += lh[r][c];
      }
      atomAddF(&vna[(size_t)g * C_ + c], run);
    }
  }
}

template <int K, int M, bool INACT>
__global__ __launch_bounds__(256) void k_mm(const float* __restrict__ A,
    const float* __restrict__ W, const float* __restrict__ bias,
    const float* __restrict__ isc, const float* __restrict__ ish,
    float* __restrict__ out, int R) {
  int idx = blockIdx.x * 256 + threadIdx.x;
  if (idx >= R * M) return;
  int row = idx / M;
  int m   = idx - row * M;
  const float* ar = A + (size_t)row * K;
  float s = bias[m];
#pragma unroll 8
  for (int k = 0; k < K; ++k) {
    float a = ar[k];
    if (INACT) a = silu_f(fmaf(a, isc[k], ish[k]));
    s = fmaf(a, W[k * M + m], s);
  }
  out[idx] = s;
}

__global__ __launch_bounds__(256) void k_pool2(const bf16* __restrict__ hb, const int* __restrict__ gstart,
                                               float* __restrict__ pooled) {
  int idx = blockIdx.x * 256 + threadIdx.x;
  if (idx >= G_ * C_) return;
  int g = idx / C_;
  int c = idx - g * C_;
  int i0 = gstart[g], i1 = gstart[g + 1];
  float s = 0.f;
  for (int i = i0; i < i1; ++i) s += toF(hb[(size_t)i * C_ + c]);
  pooled[idx] = s / fmaxf((float)(i1 - i0), 1.0f);
}

extern "C" void kernel_launch(void* const* d_in, const int* in_sizes, int n_in,
                              void* d_out, int out_size, void* d_ws, size_t ws_size,
                              hipStream_t stream) {
  (void)in_sizes; (void)n_in; (void)out_size; (void)ws_size;
  const float* x       = (const float*)d_in[0];
  const int*   ei      = (const int*)d_in[1];
  const int*   batch   = (const int*)d_in[2];
  const float* enc_w   = (const float*)d_in[4];
  const float* enc_b   = (const float*)d_in[5];
  const float* vn_emb  = (const float*)d_in[6];
  const float* vn_w1   = (const float*)d_in[7];
  const float* vn_b1   = (const float*)d_in[8];
  const float* vn_g1   = (const float*)d_in[9];
  const float* vn_be1  = (const float*)d_in[10];
  const float* vn_w2   = (const float*)d_in[11];
  const float* vn_b2   = (const float*)d_in[12];
  const float* conv_w1 = (const float*)d_in[13];
  const float* conv_b1 = (const float*)d_in[14];
  const float* conv_g1 = (const float*)d_in[15];
  const float* conv_be1= (const float*)d_in[16];
  const float* conv_w2 = (const float*)d_in[17];
  const float* conv_b2 = (const float*)d_in[18];
  const float* bn_g    = (const float*)d_in[19];
  const float* bn_b    = (const float*)d_in[20];
  const float* h_w1    = (const float*)d_in[21];
  const float* h_b1    = (const float*)d_in[22];
  const float* h_g1    = (const float*)d_in[23];
  const float* h_be1   = (const float*)d_in[24];
  const float* h_w2    = (const float*)d_in[25];
  const float* h_b2    = (const float*)d_in[26];
  const float* h_g2    = (const float*)d_in[27];
  const float* h_be2   = (const float*)d_in[28];
  const float* h_w3    = (const float*)d_in[29];
  const float* h_b3    = (const float*)d_in[30];
  float* out = (float*)d_out;

  const int* e_src = ei;
  const int* e_tgt = ei + E_;

  char* p = (char*)d_ws;
  auto alloc = [&](size_t bytes) -> char* {
    char* r = p;
    p += (bytes + 15) & ~size_t(15);
    return r;
  };
  bf16*   hbf    = (bf16*)  alloc((size_t)TOT_ * C_ * 2);
  float*  vnaf   = (float*) alloc((size_t)G_ * C_ * 4);
  bf16*   vtb    = (bf16*)  alloc((size_t)G_ * C_ * 2);
  float*  pooled = (float*) alloc((size_t)G_ * C_ * 4);
  float*  t1     = (float*) alloc((size_t)G_ * 48 * 4);
  float*  t2     = (float*) alloc((size_t)G_ * 24 * 4);
  float*  scale1 = (float*) alloc(256 * 4);
  float*  shift1 = (float*) alloc(256 * 4);
  float*  scale2 = (float*) alloc(256 * 4);
  float*  shift2 = (float*) alloc(256 * 4);
  double* stbuf  = (double*)alloc((size_t)26 * 384 * 8);
  bf16*   z1     = (bf16*)  alloc((size_t)TOT_ * 2 * C_ * 2);
  bf16*   z2     = (bf16*)  alloc((size_t)TOT_ * C_ * 2);
  bf16*   encwT  = (bf16*)  alloc((size_t)C_ * FIN_ * 2);
  bf16*   w1T    = (bf16*)  alloc((size_t)L_ * 2 * C_ * C_ * 2);
  bf16*   w2T    = (bf16*)  alloc((size_t)L_ * C_ * 2 * C_ * 2);
  bf16*   vnw1T  = (bf16*)  alloc((size_t)C_ * C_ * 2);
  bf16*   vnw2T  = (bf16*)  alloc((size_t)C_ * C_ * 2);
  int*    deg    = (int*)   alloc((size_t)N_ * 4);
  int*    cur    = (int*)   alloc((size_t)N_ * 4);
  int*    rs     = (int*)   alloc((size_t)(N_ + 1) * 4);
  int*    bsum   = (int*)   alloc(512 * 4);
  int*    boff   = (int*)   alloc(512 * 4);
  int*    ssrc   = (int*)   alloc((size_t)E_ * 4);
  int*    gstart = (int*)   alloc((size_t)(G_ + 1) * 4);
  int*    perm   = (int*)   alloc((size_t)N_ * 4);
  int*    hist   = (int*)   alloc(33 * 4);
  int*    hbase  = (int*)   alloc(33 * 4);
  int*    hcurs  = (int*)   alloc(33 * 4);

  auto ST = [&](int i) { return stbuf + (size_t)i * 384; };

  // ---- preprocessing ----
  k_prep<<<gblk(319488), 256, 0, stream>>>(enc_w, conv_w1, conv_w2, vn_w1, vn_w2,
                                           encwT, w1T, w2T, vnw1T, vnw2T);

  hipMemsetAsync(deg, 0, (size_t)N_ * 4, stream);
  hipMemsetAsync(cur, 0, (size_t)N_ * 4, stream);
  hipMemsetAsync(stbuf, 0, (size_t)26 * 384 * 8, stream);
  hipMemsetAsync(hist, 0, 33 * 4, stream);
  hipMemsetAsync(hcurs, 0, 33 * 4, stream);
  k_deg_count<<<gblk(E_), 256, 0, stream>>>(e_tgt, deg);
  k_scan_local<<<N_ / 256, 256, 0, stream>>>(deg, rs, bsum);
  k_scan_bsum<<<1, 512, 0, stream>>>(bsum, boff);
  k_scan_add<<<gblk(N_ + 1), 256, 0, stream>>>(rs, boff);
  k_csr_fill<<<gblk(E_), 256, 0, stream>>>(e_src, e_tgt, rs, cur, ssrc);
  k_gbounds<<<gblk(N_ + 1), 256, 0, stream>>>(batch, gstart);
  k_deghist<<<gblk(N_), 256, 0, stream>>>(deg, hist);
  k_degbase<<<1, 64, 0, stream>>>(hist, hbase);
  k_permfill<<<gblk(N_), 256, 0, stream>>>(deg, hbase, hcurs, perm);

  // ---- encoder + VN init ----
  k_gemm<FIN_, C_, false, false, true, bf16><<<N_ / 128, 512, 0, stream>>>(
      x, encwT, enc_b, nullptr, nullptr, nullptr, 1.f, hbf, nullptr);
  k_fill_vn<<<gblk((long)G_ * C_), 256, 0, stream>>>(hbf, vn_emb);
  k_vnagg<<<G_ / 8, 192, 0, stream>>>(hbf, gstart, vnaf);

  // ---- 8 conv layers ----
  for (int i = 0; i < L_; ++i) {
    const bf16*  wt1 = w1T + (size_t)i * 2 * C_ * C_;
    const bf16*  wt2 = w2T + (size_t)i * C_ * 2 * C_;
    const float* b1  = conv_b1 + (size_t)i * 2 * C_;
    const float* g1  = conv_g1 + (size_t)i * 2 * C_;
    const float* be1 = conv_be1+ (size_t)i * 2 * C_;
    const float* b2  = conv_b2 + (size_t)i * C_;
    const float* bg  = bn_g    + (size_t)i * C_;
    const float* bb  = bn_b    + (size_t)i * C_;
    int accvna = (i < L_ - 1);

    k_gemm_agg<C_, 2 * C_><<<TOT_ / 128, 512, 0, stream>>>(
        hbf, batch, rs, ssrc, vnaf, perm, wt1, b1, z1, ST(i));

    k_gemm<2 * C_, C_, true, true, false, bf16><<<TOT_ / 128, 512, 0, stream>>>(
        z1, wt2, b2, ST(i), g1, be1, (float)TOT_, z2, ST(8 + i));

    if (accvna) hipMemsetAsync(vnaf, 0, (size_t)G_ * C_ * 4, stream);
    k_update<<<TOT_ / 16, 192, 0, stream>>>(z2, hbf, ST(8 + i), bg, bb, i > 0,
                                            vnaf, batch, accvna);

    if (i < L_ - 1) {
      k_gemm<C_, C_, false, true, false, bf16><<<G_ / 128, 512, 0, stream>>>(
          hbf + (size_t)N_ * C_, vnw1T, vn_b1, nullptr, nullptr, nullptr, 1.f, vtb, ST(16 + i));
      k_gemm<C_, C_, true, false, false, bf16><<<G_ / 128, 512, 0, stream>>>(
          vtb, vnw2T, vn_b2, ST(16 + i), vn_g1, vn_be1, (float)G_,
          hbf + (size_t)N_ * C_, nullptr);
    }
  }

  // ---- mean pool ----
  k_pool2<<<gblk((long)G_ * C_), 256, 0, stream>>>(hbf, gstart, pooled);

  // ---- head MLP ----
  k_mm<C_, 48, false><<<gblk((long)G_ * 48), 256, 0, stream>>>(
      pooled, h_w1, h_b1, nullptr, nullptr, t1, G_);
  k_bnstats<48, float><<<64, 48, 0, stream>>>(t1, G_, ST(23));
  k_bnfin<48><<<1, 48, 0, stream>>>(ST(23), G_, h_g1, h_be1, scale1, shift1);

  k_mm<48, 24, true><<<gblk((long)G_ * 24), 256, 0, stream>>>(
      t1, h_w2, h_b2, scale1, shift1, t2, G_);
  k_bnstats<24, float><<<64, 24, 0, stream>>>(t2, G_, ST(24));
  k_bnfin<24><<<1, 24, 0, stream>>>(ST(24), G_, h_g2, h_be2, scale2, shift2);

  k_mm<24, 5, true><<<gblk((long)G_ * 5), 256, 0, stream>>>(
      t2, h_w3, h_b3, scale2, shift2, out, G_);
}